// Round 16
// baseline (242.948 us; speedup 1.0000x reference)
//
#include <hip/hip_runtime.h>
#include <cstdint>
#include <cstddef>

// ---------------------------------------------------------------- types
typedef float  f32x4 __attribute__((ext_vector_type(4)));
typedef short  s16x8 __attribute__((ext_vector_type(8)));
typedef __bf16 bf16x8 __attribute__((ext_vector_type(8)));

static __device__ __forceinline__ f32x4 mfma16(s16x8 a, s16x8 b, f32x4 c) {
    return __builtin_amdgcn_mfma_f32_16x16x32_bf16(
        __builtin_bit_cast(bf16x8, a), __builtin_bit_cast(bf16x8, b), c, 0, 0, 0);
}

static __device__ __forceinline__ unsigned short f2bf(float f) {
    unsigned int u = __builtin_bit_cast(unsigned int, f);
    u = (u + 0x7fffu + ((u >> 16) & 1u)) >> 16;
    return (unsigned short)u;
}
static __device__ __forceinline__ float bf2f(unsigned short h) {
    unsigned int u = ((unsigned int)h) << 16;
    return __builtin_bit_cast(float, u);
}

// DMA global -> LDS, 16 B per lane (dest = wave-uniform base + lane*16)
static __device__ __forceinline__ void dma16(const void* g, void* l) {
    __builtin_amdgcn_global_load_lds(
        (const __attribute__((address_space(1))) void*)g,
        (__attribute__((address_space(3))) void*)l, 16, 0, 0);
}

#define COEF 0.08838834764831845f

// ---------------------------------------------------------------- prep (r15 verbatim)
__global__ __launch_bounds__(256) void k_prep(
    const float* __restrict__ Wkey, const float* __restrict__ Wval,
    const float* __restrict__ vloc, const float* __restrict__ vlscl, const float* __restrict__ nview,
    const float* __restrict__ aoloc, const float* __restrict__ aoscl, const float* __restrict__ nobj,
    const float* __restrict__ abloc, const float* __restrict__ abscl, const float* __restrict__ nbck,
    const float* __restrict__ Wi, const float* __restrict__ Wh,
    const float* __restrict__ W1, const float* __restrict__ W2,
    unsigned short* __restrict__ Wt, unsigned short* __restrict__ qbf,
    float* __restrict__ sview, float* __restrict__ sattr,
    unsigned short* __restrict__ Wib, unsigned short* __restrict__ Whb,
    unsigned short* __restrict__ W1b, unsigned short* __restrict__ W2b)
{
    int blk = blockIdx.x, t = threadIdx.x;
    if (blk < 320) {
        float v = (blk < 128) ? Wkey[t * 128 + blk] : Wval[t * 192 + (blk - 128)];
        Wt[blk * 256 + t] = f2bf(v);
    } else if (blk < 356) {
        int g = (blk - 320) * 256 + t;
        if (g < 2048) {
            int d = g & 63;
            sview[g] = vloc[d] + __expf(vlscl[d]) * nview[g];
        } else {
            int u = g - 2048;               // [b][s][128]
            int b = u / 896, r = u % 896, s = r >> 7, d = r & 127;
            float val;
            if (s < 6) val = aoloc[d] + __expf(aoscl[d]) * nobj[(b * 6 + s) * 128 + d];
            else       val = abloc[d] + __expf(abscl[d]) * nbck[b * 128 + d];
            sattr[u] = val;
        }
    } else if (blk < 360) {
        for (int e = (blk - 356) * 256 + t; e < 32 * 9 * 128; e += 1024) {
            int bv = e / 1152, r = e % 1152, s = 7 + r / 128, k = r & 127;
            qbf[(bv * 16 + s) * 128 + k] = 0;
        }
    } else {
        const float* srcp; unsigned short* dstp; int g4;
        if (blk < 468)      { srcp = Wi; dstp = Wib; g4 = (blk - 360) * 256 + t; }
        else if (blk < 576) { srcp = Wh; dstp = Whb; g4 = (blk - 468) * 256 + t; }
        else if (blk < 624) { srcp = W1; dstp = W1b; g4 = (blk - 576) * 256 + t; }
        else                { srcp = W2; dstp = W2b; g4 = (blk - 624) * 256 + t; }
        float4 v = *(const float4*)(srcp + g4 * 4);
        unsigned u0 = (unsigned)f2bf(v.x) | ((unsigned)f2bf(v.y) << 16);
        unsigned u1 = (unsigned)f2bf(v.z) | ((unsigned)f2bf(v.w) << 16);
        *(uint2*)(dstp + g4 * 4) = make_uint2(u0, u1);
    }
}

// ---------------------------------------------------------------- phase A 1/2: LN stream -> pre-swizzled tiled bf16 image
// xb tile b (32 KB) = exact LDS image k_gemm wants: byte
//   tile*32768 + lrow*512 + ((lane*8) ^ ((lrow&7)<<4))
__global__ __launch_bounds__(256) void k_ln(
    const float* __restrict__ x, const float* __restrict__ lng, const float* __restrict__ lnb,
    unsigned short* __restrict__ xb)
{
    const int lane = threadIdx.x & 63;
    const long row = (long)blockIdx.x * 4 + (threadIdx.x >> 6);
    float4 xv = *(const float4*)(x + row * 256 + lane * 4);
    float s1 = xv.x + xv.y + xv.z + xv.w;
    float s2 = xv.x * xv.x + xv.y * xv.y + xv.z * xv.z + xv.w * xv.w;
    #pragma unroll
    for (int o = 32; o > 0; o >>= 1) { s1 += __shfl_xor(s1, o); s2 += __shfl_xor(s2, o); }
    float mean = s1 * (1.f / 256.f);
    float var  = s2 * (1.f / 256.f) - mean * mean;
    float rstd = rsqrtf(var + 1e-5f);
    float4 gv = *(const float4*)(lng + lane * 4);
    float4 bv = *(const float4*)(lnb + lane * 4);
    float y0 = (xv.x - mean) * rstd * gv.x + bv.x;
    float y1 = (xv.y - mean) * rstd * gv.y + bv.y;
    float y2 = (xv.z - mean) * rstd * gv.z + bv.z;
    float y3 = (xv.w - mean) * rstd * gv.w + bv.w;
    unsigned u0 = (unsigned)f2bf(y0) | ((unsigned)f2bf(y1) << 16);
    unsigned u1 = (unsigned)f2bf(y2) | ((unsigned)f2bf(y3) << 16);
    long tile = row >> 6; int lrow = (int)(row & 63);
    long off = tile * 32768 + (long)(lrow * 512 + ((lane * 8) ^ ((lrow & 7) << 4)));
    *(uint2*)((char*)xb + off) = make_uint2(u0, u1);
}

// ---------------------------------------------------------------- phase A 2/2: DMA-staged GEMM (r1 MFMA body + epilogue)
__global__ __launch_bounds__(256) void k_gemm(
    const unsigned short* __restrict__ xb, const unsigned short* __restrict__ Wt,
    unsigned short* __restrict__ xkv)
{
    __shared__ unsigned short lds[64 * 320];        // 40 KB; staging uses first 32 KB
    const int t = threadIdx.x, wave = t >> 6, lane = t & 63;
    const int l15 = lane & 15, lg = lane >> 4;
    const long rowbase = (long)blockIdx.x * 64;

    // ---- stage: 8 x 16B DMA per thread, LDS written linearly (image pre-swizzled)
    const char* src = (const char*)xb + (long)blockIdx.x * 32768;
    #pragma unroll
    for (int i = 0; i < 8; ++i) {
        int off = i * 4096 + t * 16;
        dma16(src + off, (char*)lds + off);
    }
    __syncthreads();

    // ---- GEMM: wave owns 80 cols (5 n-tiles), all 64 rows (4 m-tiles)  [r1 verbatim]
    f32x4 acc[4][5];
    #pragma unroll
    for (int mt = 0; mt < 4; ++mt)
        #pragma unroll
        for (int nt = 0; nt < 5; ++nt) acc[mt][nt] = (f32x4){0.f, 0.f, 0.f, 0.f};

    const int nb = wave * 80;
    #pragma unroll
    for (int kk = 0; kk < 8; ++kk) {
        s16x8 a[4], b[5];
        #pragma unroll
        for (int mt = 0; mt < 4; ++mt) {
            int row = mt * 16 + l15;
            int off = row * 512 + ((kk * 64 + lg * 16) ^ ((row & 7) << 4));
            a[mt] = *(const s16x8*)((char*)lds + off);
        }
        #pragma unroll
        for (int nt = 0; nt < 5; ++nt) {
            int col = nb + nt * 16 + l15;
            b[nt] = *(const s16x8*)(Wt + col * 256 + kk * 32 + lg * 8);
        }
        #pragma unroll
        for (int mt = 0; mt < 4; ++mt)
            #pragma unroll
            for (int nt = 0; nt < 5; ++nt)
                acc[mt][nt] = mfma16(a[mt], b[nt], acc[mt][nt]);
    }
    __syncthreads();

    #pragma unroll
    for (int mt = 0; mt < 4; ++mt)
        #pragma unroll
        for (int nt = 0; nt < 5; ++nt)
            #pragma unroll
            for (int rg = 0; rg < 4; ++rg) {
                int row = mt * 16 + lg * 4 + rg;
                int col = nb + nt * 16 + l15;
                lds[row * 320 + col] = f2bf(acc[mt][nt][rg]);
            }
    __syncthreads();
    const uint4* srcc = (const uint4*)lds;
    uint4* dst = (uint4*)(xkv + rowbase * 320);
    #pragma unroll
    for (int j = 0; j < 10; ++j) dst[j * 256 + t] = srcc[j * 256 + t];
}

// ---------------------------------------------------------------- phase A fallback (round-1 verbatim fused)
__global__ __launch_bounds__(256) void k_lnkv(
    const float* __restrict__ x, const float* __restrict__ lng, const float* __restrict__ lnb,
    const unsigned short* __restrict__ Wt, unsigned short* __restrict__ xkv)
{
    __shared__ unsigned short lds[64 * 320];        // 40 KB
    const int t = threadIdx.x, wave = t >> 6, lane = t & 63;
    const int l15 = lane & 15, lg = lane >> 4;
    const long rowbase = (long)blockIdx.x * 64;

    float4 gv = *(const float4*)(lng + lane * 4);
    float4 bv = *(const float4*)(lnb + lane * 4);
    for (int r = 0; r < 16; ++r) {
        int row = wave * 16 + r;
        float4 xv = *(const float4*)(x + (rowbase + row) * 256 + lane * 4);
        float s1 = xv.x + xv.y + xv.z + xv.w;
        float s2 = xv.x * xv.x + xv.y * xv.y + xv.z * xv.z + xv.w * xv.w;
        #pragma unroll
        for (int o = 32; o > 0; o >>= 1) { s1 += __shfl_xor(s1, o); s2 += __shfl_xor(s2, o); }
        float mean = s1 * (1.f / 256.f);
        float var  = s2 * (1.f / 256.f) - mean * mean;
        float rstd = rsqrtf(var + 1e-5f);
        float y0 = (xv.x - mean) * rstd * gv.x + bv.x;
        float y1 = (xv.y - mean) * rstd * gv.y + bv.y;
        float y2 = (xv.z - mean) * rstd * gv.z + bv.z;
        float y3 = (xv.w - mean) * rstd * gv.w + bv.w;
        unsigned int u0 = (unsigned)f2bf(y0) | ((unsigned)f2bf(y1) << 16);
        unsigned int u1 = (unsigned)f2bf(y2) | ((unsigned)f2bf(y3) << 16);
        int off = row * 512 + ((lane * 8) ^ ((row & 7) << 4));
        *(uint2*)((char*)lds + off) = make_uint2(u0, u1);
    }
    __syncthreads();

    f32x4 acc[4][5];
    #pragma unroll
    for (int mt = 0; mt < 4; ++mt)
        #pragma unroll
        for (int nt = 0; nt < 5; ++nt) acc[mt][nt] = (f32x4){0.f, 0.f, 0.f, 0.f};

    const int nb = wave * 80;
    #pragma unroll
    for (int kk = 0; kk < 8; ++kk) {
        s16x8 a[4], b[5];
        #pragma unroll
        for (int mt = 0; mt < 4; ++mt) {
            int row = mt * 16 + l15;
            int off = row * 512 + ((kk * 64 + lg * 16) ^ ((row & 7) << 4));
            a[mt] = *(const s16x8*)((char*)lds + off);
        }
        #pragma unroll
        for (int nt = 0; nt < 5; ++nt) {
            int col = nb + nt * 16 + l15;
            b[nt] = *(const s16x8*)(Wt + col * 256 + kk * 32 + lg * 8);
        }
        #pragma unroll
        for (int mt = 0; mt < 4; ++mt)
            #pragma unroll
            for (int nt = 0; nt < 5; ++nt)
                acc[mt][nt] = mfma16(a[mt], b[nt], acc[mt][nt]);
    }
    __syncthreads();

    #pragma unroll
    for (int mt = 0; mt < 4; ++mt)
        #pragma unroll
        for (int nt = 0; nt < 5; ++nt)
            #pragma unroll
            for (int rg = 0; rg < 4; ++rg) {
                int row = mt * 16 + lg * 4 + rg;
                int col = nb + nt * 16 + l15;
                lds[row * 320 + col] = f2bf(acc[mt][nt][rg]);
            }
    __syncthreads();
    const uint4* src = (const uint4*)lds;
    uint4* dst = (uint4*)(xkv + rowbase * 320);
    #pragma unroll
    for (int j = 0; j < 10; ++j) dst[j * 256 + t] = src[j * 256 + t];
}

// ---------------------------------------------------------------- per-iter: q v3 (r15 verbatim)
__global__ __launch_bounds__(384) void k_qry(
    const float* __restrict__ sview, const float* __restrict__ sattr,
    const float* __restrict__ fnewp, int use_fnew,
    const float* __restrict__ lng, const float* __restrict__ lnb,
    const float* __restrict__ Wq, float* __restrict__ full, unsigned short* __restrict__ qbf)
{
    int row = blockIdx.x;                  // bv*7 + s
    int bv = row / 7, s = row % 7, b = bv >> 2;
    int j = threadIdx.x;
    __shared__ float fr[192];
    __shared__ float part[384];
    __shared__ float red[8];
    float v = 0.f;
    if (j < 192) {
        if (use_fnew) {
            if (j < 64) {
                float a = 0.f;
                #pragma unroll
                for (int sp = 0; sp < 7; ++sp) a += fnewp[(bv * 7 + sp) * 192 + j];
                v = a * (1.f / 7.f);
            } else {
                float a = 0.f;
                #pragma unroll
                for (int vv = 0; vv < 4; ++vv) a += fnewp[((b * 4 + vv) * 7 + s) * 192 + j];
                v = a * 0.25f;
            }
        } else {
            v = (j < 64) ? sview[bv * 64 + j] : sattr[(b * 7 + s) * 128 + (j - 64)];
        }
        full[row * 192 + j] = v;
        float s1 = v, s2 = v * v;
        #pragma unroll
        for (int o = 32; o > 0; o >>= 1) { s1 += __shfl_xor(s1, o); s2 += __shfl_xor(s2, o); }
        int wave = j >> 6, lane = j & 63;
        if (lane == 0) { red[wave] = s1; red[4 + wave] = s2; }
    }
    __syncthreads();
    if (j < 192) {
        float ts = red[0] + red[1] + red[2], ts2 = red[4] + red[5] + red[6];
        float mean = ts * (1.f / 192.f);
        float var  = ts2 * (1.f / 192.f) - mean * mean;
        float rstd = rsqrtf(var + 1e-5f);
        fr[j] = (v - mean) * rstd * lng[j] + lnb[j];
    }
    __syncthreads();
    {
        int c = j & 127, seg = j >> 7;               // 3 segments x 64 k
        float acc = 0.f;
        #pragma unroll
        for (int k = 0; k < 64; ++k) acc += fr[seg * 64 + k] * Wq[(seg * 64 + k) * 128 + c];
        part[j] = acc;
    }
    __syncthreads();
    if (j < 128) {
        float acc = part[j] + part[128 + j] + part[256 + j];
        qbf[(bv * 16 + s) * 128 + j] = f2bf(acc * COEF);
    }
}

// ---------------------------------------------------------------- per-iter: fused attn+upd v2 (r15 verbatim)
__global__ __launch_bounds__(256) void k_attu(
    const unsigned short* __restrict__ qbf, const unsigned short* __restrict__ xkv,
    float* __restrict__ pU, float* __restrict__ pZ)
{
    int blk = blockIdx.x;                  // 1024 = 32 bv * 32 chunks(128 n)
    int bv = blk >> 5, chunk = blk & 31;
    int n0 = chunk * 128;
    int t = threadIdx.x, wave = t >> 6, lane = t & 63;
    int l15 = lane & 15, lg = lane >> 4;
    __shared__ float wl[128 * 8];

    s16x8 aq[4];
    const unsigned short* qrow = qbf + (bv * 16 + l15) * 128 + lg * 8;
    #pragma unroll
    for (int kk = 0; kk < 4; ++kk) aq[kk] = *(const s16x8*)(qrow + kk * 32);

    #pragma unroll
    for (int batch = 0; batch < 2; ++batch) {
        int nloc = batch * 64 + wave * 16;
        const unsigned short* xr = xkv + ((long)(bv * 4096 + n0 + nloc + l15)) * 320 + lg * 8;
        f32x4 acc = (f32x4){0.f, 0.f, 0.f, 0.f};
        #pragma unroll
        for (int kk = 0; kk < 4; ++kk) {
            s16x8 bfr = *(const s16x8*)(xr + kk * 32);
            acc = mfma16(aq[kk], bfr, acc);
        }
        float o0 = __shfl_xor(acc[0], 16), o1 = __shfl_xor(acc[1], 16);
        float o2 = __shfl_xor(acc[2], 16), o3 = __shfl_xor(acc[3], 16);
        bool hi = (lg & 1);
        float v0 = hi ? o0 : acc[0], v1 = hi ? o1 : acc[1];
        float v2 = hi ? o2 : acc[2], v3 = hi ? o3 : acc[3];
        float v4 = hi ? acc[0] : o0, v5 = hi ? acc[1] : o1, v6 = hi ? acc[2] : o2;
        float m = fmaxf(fmaxf(fmaxf(v0, v1), fmaxf(v2, v3)), fmaxf(fmaxf(v4, v5), v6));
        float e0 = __expf(v0 - m), e1 = __expf(v1 - m), e2 = __expf(v2 - m), e3 = __expf(v3 - m);
        float e4 = __expf(v4 - m), e5 = __expf(v5 - m), e6 = __expf(v6 - m);
        float inv = 1.f / (e0 + e1 + e2 + e3 + e4 + e5 + e6);
        if (lg < 2) {
            int n = nloc + l15;                // LOCAL row index 0..127
            float4 out = (lg == 0) ? make_float4(e0 * inv, e1 * inv, e2 * inv, e3 * inv)
                                   : make_float4(e4 * inv, e5 * inv, e6 * inv, 0.f);
            *(float4*)(wl + n * 8 + lg * 4) = out;
        }
    }
    __syncthreads();

    {
        f32x4 uacc[3];
        #pragma unroll
        for (int it = 0; it < 3; ++it) uacc[it] = (f32x4){0.f, 0.f, 0.f, 0.f};
        const unsigned short* vbase = xkv + ((long)(bv * 4096 + n0)) * 320 + 128;

        #pragma unroll
        for (int kb = 0; kb < 4; ++kb) {
            s16x8 aw = (s16x8){0, 0, 0, 0, 0, 0, 0, 0};
            if (l15 < 8) {
                #pragma unroll
                for (int j2 = 0; j2 < 8; ++j2)
                    aw[j2] = (short)f2bf(wl[(kb * 32 + lg * 8 + j2) * 8 + l15]);
            }
            #pragma unroll
            for (int it = 0; it < 3; ++it) {
                int col = wave * 48 + it * 16 + l15;
                s16x8 bw;
                #pragma unroll
                for (int j2 = 0; j2 < 8; ++j2)
                    bw[j2] = (short)vbase[(long)(kb * 32 + lg * 8 + j2) * 320 + col];
                uacc[it] = mfma16(aw, bw, uacc[it]);
            }
        }

        long base = (((long)bv * 32 + chunk) * 7) * 192;
        #pragma unroll
        for (int it = 0; it < 3; ++it) {
            int col = wave * 48 + it * 16 + l15;
            #pragma unroll
            for (int rg = 0; rg < 4; ++rg) {
                int s = lg * 4 + rg;
                if (s < 7) pU[base + s * 192 + col] = uacc[it][rg];
            }
        }
    }

    if (t < 112) {
        int s = t >> 4, part = t & 15;
        float z = 0.f;
        #pragma unroll
        for (int k = 0; k < 8; ++k) z += wl[(part + 16 * k) * 8 + s];
        #pragma unroll
        for (int o = 8; o > 0; o >>= 1) z += __shfl_xor(z, o);
        if (part == 0) pZ[(bv * 32 + chunk) * 7 + s] = z;
    }
}

// ---------------------------------------------------------------- per-iter: GRU+MLP v4 (r15 verbatim)
__global__ __launch_bounds__(576) void k_gru(
    const float* __restrict__ pU, const float* __restrict__ pZ, const float* __restrict__ full,
    const unsigned short* __restrict__ Wib, const unsigned short* __restrict__ Whb,
    const float* __restrict__ bi, const float* __restrict__ bh,
    const float* __restrict__ lng, const float* __restrict__ lnb,
    const unsigned short* __restrict__ W1b, const float* __restrict__ b1,
    const unsigned short* __restrict__ W2b, const float* __restrict__ b2,
    float* __restrict__ fnew)
{
    int row = blockIdx.x;                  // bv*7 + s
    int bv = row / 7, s = row % 7;
    int j = threadIdx.x;
    __shared__ float u[192], h[192], gi[576], gh[576], lnm[192], h1[256], red[8];

    if (j < 192) {
        float u0 = 0.f, u1 = 0.f, u2 = 0.f, u3 = 0.f;
        #pragma unroll 4
        for (int c = 0; c < 32; c += 4) {
            u0 += pU[(((long)bv * 32 + c + 0) * 7 + s) * 192 + j];
            u1 += pU[(((long)bv * 32 + c + 1) * 7 + s) * 192 + j];
            u2 += pU[(((long)bv * 32 + c + 2) * 7 + s) * 192 + j];
            u3 += pU[(((long)bv * 32 + c + 3) * 7 + s) * 192 + j];
        }
        float z0 = 0.f, z1 = 0.f, z2 = 0.f, z3 = 0.f;
        #pragma unroll 4
        for (int c = 0; c < 32; c += 4) {
            z0 += pZ[(bv * 32 + c + 0) * 7 + s];
            z1 += pZ[(bv * 32 + c + 1) * 7 + s];
            z2 += pZ[(bv * 32 + c + 2) * 7 + s];
            z3 += pZ[(bv * 32 + c + 3) * 7 + s];
        }
        u[j] = ((u0 + u1) + (u2 + u3)) / ((z0 + z1) + (z2 + z3));
    } else if (j < 384) {
        int jj = j - 192;
        h[jj] = full[row * 192 + jj];
    }
    __syncthreads();

    {
        float a0 = 0.f, a1 = 0.f, a2 = 0.f, a3 = 0.f;
        float b0 = 0.f, b1v = 0.f, b2v = 0.f, b3 = 0.f;
        #pragma unroll 4
        for (int k = 0; k < 192; k += 4) {
            float uk0 = u[k], uk1 = u[k + 1], uk2 = u[k + 2], uk3 = u[k + 3];
            float hk0 = h[k], hk1 = h[k + 1], hk2 = h[k + 2], hk3 = h[k + 3];
            a0  += uk0 * bf2f(Wib[(k + 0) * 576 + j]);
            a1  += uk1 * bf2f(Wib[(k + 1) * 576 + j]);
            a2  += uk2 * bf2f(Wib[(k + 2) * 576 + j]);
            a3  += uk3 * bf2f(Wib[(k + 3) * 576 + j]);
            b0  += hk0 * bf2f(Whb[(k + 0) * 576 + j]);
            b1v += hk1 * bf2f(Whb[(k + 1) * 576 + j]);
            b2v += hk2 * bf2f(Whb[(k + 2) * 576 + j]);
            b3  += hk3 * bf2f(Whb[(k + 3) * 576 + j]);
        }
        gi[j] = ((a0 + a1) + (a2 + a3)) + bi[j];
        gh[j] = ((b0 + b1v) + (b2v + b3)) + bh[j];
    }
    __syncthreads();

    float mn = 0.f;
    if (j < 192) {
        float hv = h[j];
        float r  = 1.f / (1.f + __expf(-(gi[j] + gh[j])));
        float z  = 1.f / (1.f + __expf(-(gi[192 + j] + gh[192 + j])));
        float nn = tanhf(gi[384 + j] + r * gh[384 + j]);
        mn = (1.f - z) * nn + z * hv;

        float s1 = mn, s2 = mn * mn;
        #pragma unroll
        for (int o = 32; o > 0; o >>= 1) { s1 += __shfl_xor(s1, o); s2 += __shfl_xor(s2, o); }
        int wave = j >> 6, lane = j & 63;
        if (lane == 0) { red[wave] = s1; red[4 + wave] = s2; }
    }
    __syncthreads();
    if (j < 192) {
        float ts = red[0] + red[1] + red[2], ts2 = red[4] + red[5] + red[6];
        float mean = ts * (1.f / 192.f);
        float var  = ts2 * (1.f / 192.f) - mean * mean;
        float rstd = rsqrtf(var + 1e-5f);
        lnm[j] = (mn - mean) * rstd * lng[j] + lnb[j];
    }
    __syncthreads();

    if (j < 256) {
        float a0 = 0.f, a1 = 0.f, a2 = 0.f, a3 = 0.f;
        #pragma unroll 4
        for (int k = 0; k < 192; k += 4) {
            a0 += lnm[k + 0] * bf2f(W1b[(k + 0) * 256 + j]);
            a1 += lnm[k + 1] * bf2f(W1b[(k + 1) * 256 + j]);
            a2 += lnm[k + 2] * bf2f(W1b[(k + 2) * 256 + j]);
            a3 += lnm[k + 3] * bf2f(W1b[(k + 3) * 256 + j]);
        }
        h1[j] = fmaxf(((a0 + a1) + (a2 + a3)) + b1[j], 0.f);
    }
    __syncthreads();

    if (j < 192) {
        float a0 = 0.f, a1 = 0.f, a2 = 0.f, a3 = 0.f;
        #pragma unroll 4
        for (int c = 0; c < 256; c += 4) {
            a0 += h1[c + 0] * bf2f(W2b[(c + 0) * 192 + j]);
            a1 += h1[c + 1] * bf2f(W2b[(c + 1) * 192 + j]);
            a2 += h1[c + 2] * bf2f(W2b[(c + 2) * 192 + j]);
            a3 += h1[c + 3] * bf2f(W2b[(c + 3) * 192 + j]);
        }
        fnew[row * 192 + j] = mn + (((a0 + a1) + (a2 + a3)) + b2[j]);
    }
}

// ---------------------------------------------------------------- final: slot means -> d_out (r15 verbatim)
__global__ __launch_bounds__(256) void k_means(
    const float* __restrict__ fnew, float* __restrict__ oview, float* __restrict__ oattr)
{
    int t = blockIdx.x * 256 + threadIdx.x;
    if (t < 2048) {
        int bv = t >> 6, d = t & 63;
        float a = 0.f;
        #pragma unroll
        for (int s = 0; s < 7; ++s) a += fnew[(bv * 7 + s) * 192 + d];
        oview[t] = a * (1.f / 7.f);
    } else if (t < 9216) {
        int u = t - 2048;
        int b = u / 896, r = u % 896, s = r >> 7, d = r & 127;
        float a = 0.f;
        #pragma unroll
        for (int v = 0; v < 4; ++v) a += fnew[((b * 4 + v) * 7 + s) * 192 + 64 + d];
        oattr[u] = a * 0.25f;
    }
}

// ---------------------------------------------------------------- host
extern "C" void kernel_launch(void* const* d_in, const int* in_sizes, int n_in,
                              void* d_out, int out_size, void* d_ws, size_t ws_size,
                              hipStream_t stream)
{
    const float* x          = (const float*)d_in[0];
    const float* noise_view = (const float*)d_in[1];
    const float* noise_obj  = (const float*)d_in[2];
    const float* noise_bck  = (const float*)d_in[3];
    const float* ln_in_g    = (const float*)d_in[4];
    const float* ln_in_b    = (const float*)d_in[5];
    const float* ln_qry_g   = (const float*)d_in[6];
    const float* ln_qry_b   = (const float*)d_in[7];
    const float* ln_res_g   = (const float*)d_in[8];
    const float* ln_res_b   = (const float*)d_in[9];
    const float* view_loc   = (const float*)d_in[10];
    const float* view_lscl  = (const float*)d_in[11];
    const float* ao_loc     = (const float*)d_in[12];
    const float* ao_scl     = (const float*)d_in[13];
    const float* ab_loc     = (const float*)d_in[14];
    const float* ab_scl     = (const float*)d_in[15];
    const float* W_qry      = (const float*)d_in[16];
    const float* W_key      = (const float*)d_in[17];
    const float* W_val      = (const float*)d_in[18];
    const float* gru_Wi     = (const float*)d_in[19];
    const float* gru_Wh     = (const float*)d_in[20];
    const float* gru_bi     = (const float*)d_in[21];
    const float* gru_bh     = (const float*)d_in[22];
    const float* mlp_W1     = (const float*)d_in[23];
    const float* mlp_b1     = (const float*)d_in[24];
    const float* mlp_W2     = (const float*)d_in[25];
    const float* mlp_b2     = (const float*)d_in[26];

    char* ws = (char*)d_ws;
    size_t off = 0;
    auto alloc = [&](size_t bytes) { void* p = ws + off; off += (bytes + 255) & ~255ULL; return p; };
    unsigned short* xkv = (unsigned short*)alloc(131072UL * 320 * 2);   // 80 MB
    unsigned short* Wt  = (unsigned short*)alloc(320UL * 256 * 2);
    unsigned short* qbf = (unsigned short*)alloc(32UL * 16 * 128 * 2);
    float* pU    = (float*)alloc(32UL * 32 * 7 * 192 * 4);              // 5.5 MB
    float* pZ    = (float*)alloc(32UL * 32 * 7 * 4);
    float* fullb = (float*)alloc(224UL * 192 * 4);
    float* fnew  = (float*)alloc(224UL * 192 * 4);
    float* sview = (float*)alloc(2048UL * 4);
    float* sattr = (float*)alloc(7168UL * 4);
    unsigned short* Wib = (unsigned short*)alloc(110592UL * 2);
    unsigned short* Whb = (unsigned short*)alloc(110592UL * 2);
    unsigned short* W1b = (unsigned short*)alloc(49152UL * 2);
    unsigned short* W2b = (unsigned short*)alloc(49152UL * 2);
    unsigned short* xb  = (unsigned short*)alloc(131072UL * 256 * 2);   // 64 MB (split path)
    bool use_split = (off <= ws_size);

    k_prep<<<dim3(672), dim3(256), 0, stream>>>(
        W_key, W_val, view_loc, view_lscl, noise_view,
        ao_loc, ao_scl, noise_obj, ab_loc, ab_scl, noise_bck,
        gru_Wi, gru_Wh, mlp_W1, mlp_W2,
        Wt, qbf, sview, sattr, Wib, Whb, W1b, W2b);
    if (use_split) {
        k_ln  <<<dim3(32768), dim3(256), 0, stream>>>(x, ln_in_g, ln_in_b, xb);
        k_gemm<<<dim3(2048),  dim3(256), 0, stream>>>(xb, Wt, xkv);
    } else {
        k_lnkv<<<dim3(2048), dim3(256), 0, stream>>>(x, ln_in_g, ln_in_b, Wt, xkv);
    }

    for (int it = 0; it < 3; ++it) {
        k_qry<<<dim3(224), dim3(384), 0, stream>>>(sview, sattr, fnew, (it > 0) ? 1 : 0,
                                                   ln_qry_g, ln_qry_b, W_qry, fullb, qbf);
        k_attu<<<dim3(1024), dim3(256), 0, stream>>>(qbf, xkv, pU, pZ);
        k_gru<<<dim3(224), dim3(576), 0, stream>>>(pU, pZ, fullb, Wib, Whb, gru_bi, gru_bh,
                                                   ln_res_g, ln_res_b, W1b, mlp_b1, W2b, mlp_b2, fnew);
    }
    k_means<<<dim3(36), dim3(256), 0, stream>>>(fnew, (float*)d_out, ((float*)d_out) + 2048);
}

// Round 17
// 207.582 us; speedup vs baseline: 1.1704x; 1.1704x over previous
//
#include <hip/hip_runtime.h>
#include <cstdint>
#include <cstddef>

// ---------------------------------------------------------------- types
typedef float  f32x4 __attribute__((ext_vector_type(4)));
typedef short  s16x8 __attribute__((ext_vector_type(8)));
typedef __bf16 bf16x8 __attribute__((ext_vector_type(8)));

static __device__ __forceinline__ f32x4 mfma16(s16x8 a, s16x8 b, f32x4 c) {
    return __builtin_amdgcn_mfma_f32_16x16x32_bf16(
        __builtin_bit_cast(bf16x8, a), __builtin_bit_cast(bf16x8, b), c, 0, 0, 0);
}

static __device__ __forceinline__ unsigned short f2bf(float f) {
    unsigned int u = __builtin_bit_cast(unsigned int, f);
    u = (u + 0x7fffu + ((u >> 16) & 1u)) >> 16;
    return (unsigned short)u;
}
static __device__ __forceinline__ float bf2f(unsigned short h) {
    unsigned int u = ((unsigned int)h) << 16;
    return __builtin_bit_cast(float, u);
}

#define COEF 0.08838834764831845f

// ---------------------------------------------------------------- prep (r15 verbatim)
__global__ __launch_bounds__(256) void k_prep(
    const float* __restrict__ Wkey, const float* __restrict__ Wval,
    const float* __restrict__ vloc, const float* __restrict__ vlscl, const float* __restrict__ nview,
    const float* __restrict__ aoloc, const float* __restrict__ aoscl, const float* __restrict__ nobj,
    const float* __restrict__ abloc, const float* __restrict__ abscl, const float* __restrict__ nbck,
    const float* __restrict__ Wi, const float* __restrict__ Wh,
    const float* __restrict__ W1, const float* __restrict__ W2,
    unsigned short* __restrict__ Wt, unsigned short* __restrict__ qbf,
    float* __restrict__ sview, float* __restrict__ sattr,
    unsigned short* __restrict__ Wib, unsigned short* __restrict__ Whb,
    unsigned short* __restrict__ W1b, unsigned short* __restrict__ W2b)
{
    int blk = blockIdx.x, t = threadIdx.x;
    if (blk < 320) {
        float v = (blk < 128) ? Wkey[t * 128 + blk] : Wval[t * 192 + (blk - 128)];
        Wt[blk * 256 + t] = f2bf(v);
    } else if (blk < 356) {
        int g = (blk - 320) * 256 + t;
        if (g < 2048) {
            int d = g & 63;
            sview[g] = vloc[d] + __expf(vlscl[d]) * nview[g];
        } else {
            int u = g - 2048;               // [b][s][128]
            int b = u / 896, r = u % 896, s = r >> 7, d = r & 127;
            float val;
            if (s < 6) val = aoloc[d] + __expf(aoscl[d]) * nobj[(b * 6 + s) * 128 + d];
            else       val = abloc[d] + __expf(abscl[d]) * nbck[b * 128 + d];
            sattr[u] = val;
        }
    } else if (blk < 360) {
        for (int e = (blk - 356) * 256 + t; e < 32 * 9 * 128; e += 1024) {
            int bv = e / 1152, r = e % 1152, s = 7 + r / 128, k = r & 127;
            qbf[(bv * 16 + s) * 128 + k] = 0;
        }
    } else {
        const float* srcp; unsigned short* dstp; int g4;
        if (blk < 468)      { srcp = Wi; dstp = Wib; g4 = (blk - 360) * 256 + t; }
        else if (blk < 576) { srcp = Wh; dstp = Whb; g4 = (blk - 468) * 256 + t; }
        else if (blk < 624) { srcp = W1; dstp = W1b; g4 = (blk - 576) * 256 + t; }
        else                { srcp = W2; dstp = W2b; g4 = (blk - 624) * 256 + t; }
        float4 v = *(const float4*)(srcp + g4 * 4);
        unsigned u0 = (unsigned)f2bf(v.x) | ((unsigned)f2bf(v.y) << 16);
        unsigned u1 = (unsigned)f2bf(v.z) | ((unsigned)f2bf(v.w) << 16);
        *(uint2*)(dstp + g4 * 4) = make_uint2(u0, u1);
    }
}

// ---------------------------------------------------------------- phase A (round-1 verbatim, measured 110.8 us — FROZEN)
__global__ __launch_bounds__(256) void k_lnkv(
    const float* __restrict__ x, const float* __restrict__ lng, const float* __restrict__ lnb,
    const unsigned short* __restrict__ Wt, unsigned short* __restrict__ xkv)
{
    __shared__ unsigned short lds[64 * 320];        // 40 KB
    const int t = threadIdx.x, wave = t >> 6, lane = t & 63;
    const int l15 = lane & 15, lg = lane >> 4;
    const long rowbase = (long)blockIdx.x * 64;

    float4 gv = *(const float4*)(lng + lane * 4);
    float4 bv = *(const float4*)(lnb + lane * 4);
    for (int r = 0; r < 16; ++r) {
        int row = wave * 16 + r;
        float4 xv = *(const float4*)(x + (rowbase + row) * 256 + lane * 4);
        float s1 = xv.x + xv.y + xv.z + xv.w;
        float s2 = xv.x * xv.x + xv.y * xv.y + xv.z * xv.z + xv.w * xv.w;
        #pragma unroll
        for (int o = 32; o > 0; o >>= 1) { s1 += __shfl_xor(s1, o); s2 += __shfl_xor(s2, o); }
        float mean = s1 * (1.f / 256.f);
        float var  = s2 * (1.f / 256.f) - mean * mean;
        float rstd = rsqrtf(var + 1e-5f);
        float y0 = (xv.x - mean) * rstd * gv.x + bv.x;
        float y1 = (xv.y - mean) * rstd * gv.y + bv.y;
        float y2 = (xv.z - mean) * rstd * gv.z + bv.z;
        float y3 = (xv.w - mean) * rstd * gv.w + bv.w;
        unsigned int u0 = (unsigned)f2bf(y0) | ((unsigned)f2bf(y1) << 16);
        unsigned int u1 = (unsigned)f2bf(y2) | ((unsigned)f2bf(y3) << 16);
        int off = row * 512 + ((lane * 8) ^ ((row & 7) << 4));
        *(uint2*)((char*)lds + off) = make_uint2(u0, u1);
    }
    __syncthreads();

    f32x4 acc[4][5];
    #pragma unroll
    for (int mt = 0; mt < 4; ++mt)
        #pragma unroll
        for (int nt = 0; nt < 5; ++nt) acc[mt][nt] = (f32x4){0.f, 0.f, 0.f, 0.f};

    const int nb = wave * 80;
    #pragma unroll
    for (int kk = 0; kk < 8; ++kk) {
        s16x8 a[4], b[5];
        #pragma unroll
        for (int mt = 0; mt < 4; ++mt) {
            int row = mt * 16 + l15;
            int off = row * 512 + ((kk * 64 + lg * 16) ^ ((row & 7) << 4));
            a[mt] = *(const s16x8*)((char*)lds + off);
        }
        #pragma unroll
        for (int nt = 0; nt < 5; ++nt) {
            int col = nb + nt * 16 + l15;
            b[nt] = *(const s16x8*)(Wt + col * 256 + kk * 32 + lg * 8);
        }
        #pragma unroll
        for (int mt = 0; mt < 4; ++mt)
            #pragma unroll
            for (int nt = 0; nt < 5; ++nt)
                acc[mt][nt] = mfma16(a[mt], b[nt], acc[mt][nt]);
    }
    __syncthreads();

    #pragma unroll
    for (int mt = 0; mt < 4; ++mt)
        #pragma unroll
        for (int nt = 0; nt < 5; ++nt)
            #pragma unroll
            for (int rg = 0; rg < 4; ++rg) {
                int row = mt * 16 + lg * 4 + rg;
                int col = nb + nt * 16 + l15;
                lds[row * 320 + col] = f2bf(acc[mt][nt][rg]);
            }
    __syncthreads();
    const uint4* src = (const uint4*)lds;
    uint4* dst = (uint4*)(xkv + rowbase * 320);
    #pragma unroll
    for (int j = 0; j < 10; ++j) dst[j * 256 + t] = src[j * 256 + t];
}

// ---------------------------------------------------------------- per-iter: q v3 (r15 verbatim)
__global__ __launch_bounds__(384) void k_qry(
    const float* __restrict__ sview, const float* __restrict__ sattr,
    const float* __restrict__ fnewp, int use_fnew,
    const float* __restrict__ lng, const float* __restrict__ lnb,
    const float* __restrict__ Wq, float* __restrict__ full, unsigned short* __restrict__ qbf)
{
    int row = blockIdx.x;                  // bv*7 + s
    int bv = row / 7, s = row % 7, b = bv >> 2;
    int j = threadIdx.x;
    __shared__ float fr[192];
    __shared__ float part[384];
    __shared__ float red[8];
    float v = 0.f;
    if (j < 192) {
        if (use_fnew) {
            if (j < 64) {
                float a = 0.f;
                #pragma unroll
                for (int sp = 0; sp < 7; ++sp) a += fnewp[(bv * 7 + sp) * 192 + j];
                v = a * (1.f / 7.f);
            } else {
                float a = 0.f;
                #pragma unroll
                for (int vv = 0; vv < 4; ++vv) a += fnewp[((b * 4 + vv) * 7 + s) * 192 + j];
                v = a * 0.25f;
            }
        } else {
            v = (j < 64) ? sview[bv * 64 + j] : sattr[(b * 7 + s) * 128 + (j - 64)];
        }
        full[row * 192 + j] = v;
        float s1 = v, s2 = v * v;
        #pragma unroll
        for (int o = 32; o > 0; o >>= 1) { s1 += __shfl_xor(s1, o); s2 += __shfl_xor(s2, o); }
        int wave = j >> 6, lane = j & 63;
        if (lane == 0) { red[wave] = s1; red[4 + wave] = s2; }
    }
    __syncthreads();
    if (j < 192) {
        float ts = red[0] + red[1] + red[2], ts2 = red[4] + red[5] + red[6];
        float mean = ts * (1.f / 192.f);
        float var  = ts2 * (1.f / 192.f) - mean * mean;
        float rstd = rsqrtf(var + 1e-5f);
        fr[j] = (v - mean) * rstd * lng[j] + lnb[j];
    }
    __syncthreads();
    {
        int c = j & 127, seg = j >> 7;               // 3 segments x 64 k
        float acc = 0.f;
        #pragma unroll
        for (int k = 0; k < 64; ++k) acc += fr[seg * 64 + k] * Wq[(seg * 64 + k) * 128 + c];
        part[j] = acc;
    }
    __syncthreads();
    if (j < 128) {
        float acc = part[j] + part[128 + j] + part[256 + j];
        qbf[(bv * 16 + s) * 128 + j] = f2bf(acc * COEF);
    }
}

// ---------------------------------------------------------------- per-iter: fused attn+upd v3 — 256-n chunks (512 blocks)
// Phase A: 4 batches of 64 n; phase B: 8 MFMA k-blocks. pU/pZ chunks -> 16.
__global__ __launch_bounds__(256) void k_attu(
    const unsigned short* __restrict__ qbf, const unsigned short* __restrict__ xkv,
    float* __restrict__ pU, float* __restrict__ pZ)
{
    int blk = blockIdx.x;                  // 512 = 32 bv * 16 chunks(256 n)
    int bv = blk >> 4, chunk = blk & 15;
    int n0 = chunk * 256;
    int t = threadIdx.x, wave = t >> 6, lane = t & 63;
    int l15 = lane & 15, lg = lane >> 4;
    __shared__ float wl[256 * 8];

    // ---- phase A: logits via MFMA + softmax over slots -> wl (4 batches of 64 n)
    s16x8 aq[4];
    const unsigned short* qrow = qbf + (bv * 16 + l15) * 128 + lg * 8;
    #pragma unroll
    for (int kk = 0; kk < 4; ++kk) aq[kk] = *(const s16x8*)(qrow + kk * 32);

    #pragma unroll
    for (int batch = 0; batch < 4; ++batch) {
        int nloc = batch * 64 + wave * 16;
        const unsigned short* xr = xkv + ((long)(bv * 4096 + n0 + nloc + l15)) * 320 + lg * 8;
        f32x4 acc = (f32x4){0.f, 0.f, 0.f, 0.f};
        #pragma unroll
        for (int kk = 0; kk < 4; ++kk) {
            s16x8 bfr = *(const s16x8*)(xr + kk * 32);
            acc = mfma16(aq[kk], bfr, acc);
        }
        float o0 = __shfl_xor(acc[0], 16), o1 = __shfl_xor(acc[1], 16);
        float o2 = __shfl_xor(acc[2], 16), o3 = __shfl_xor(acc[3], 16);
        bool hi = (lg & 1);
        float v0 = hi ? o0 : acc[0], v1 = hi ? o1 : acc[1];
        float v2 = hi ? o2 : acc[2], v3 = hi ? o3 : acc[3];
        float v4 = hi ? acc[0] : o0, v5 = hi ? acc[1] : o1, v6 = hi ? acc[2] : o2;
        float m = fmaxf(fmaxf(fmaxf(v0, v1), fmaxf(v2, v3)), fmaxf(fmaxf(v4, v5), v6));
        float e0 = __expf(v0 - m), e1 = __expf(v1 - m), e2 = __expf(v2 - m), e3 = __expf(v3 - m);
        float e4 = __expf(v4 - m), e5 = __expf(v5 - m), e6 = __expf(v6 - m);
        float inv = 1.f / (e0 + e1 + e2 + e3 + e4 + e5 + e6);
        if (lg < 2) {
            int n = nloc + l15;                // LOCAL row index 0..255
            float4 out = (lg == 0) ? make_float4(e0 * inv, e1 * inv, e2 * inv, e3 * inv)
                                   : make_float4(e4 * inv, e5 * inv, e6 * inv, 0.f);
            *(float4*)(wl + n * 8 + lg * 4) = out;
        }
    }
    __syncthreads();

    // ---- phase B: updates via MFMA over 8 k-blocks. Wave w owns i-tiles {3w..3w+2}.
    {
        f32x4 uacc[3];
        #pragma unroll
        for (int it = 0; it < 3; ++it) uacc[it] = (f32x4){0.f, 0.f, 0.f, 0.f};
        const unsigned short* vbase = xkv + ((long)(bv * 4096 + n0)) * 320 + 128;

        #pragma unroll
        for (int kb = 0; kb < 8; ++kb) {
            s16x8 aw = (s16x8){0, 0, 0, 0, 0, 0, 0, 0};
            if (l15 < 8) {                 // col 7 of wl is the 0.0 pad; rows 8..15 zero
                #pragma unroll
                for (int j2 = 0; j2 < 8; ++j2)
                    aw[j2] = (short)f2bf(wl[(kb * 32 + lg * 8 + j2) * 8 + l15]);
            }
            #pragma unroll
            for (int it = 0; it < 3; ++it) {
                int col = wave * 48 + it * 16 + l15;
                s16x8 bw;
                #pragma unroll
                for (int j2 = 0; j2 < 8; ++j2)
                    bw[j2] = (short)vbase[(long)(kb * 32 + lg * 8 + j2) * 320 + col];
                uacc[it] = mfma16(aw, bw, uacc[it]);
            }
        }

        long base = (((long)bv * 16 + chunk) * 7) * 192;
        #pragma unroll
        for (int it = 0; it < 3; ++it) {
            int col = wave * 48 + it * 16 + l15;
            #pragma unroll
            for (int rg = 0; rg < 4; ++rg) {
                int s = lg * 4 + rg;       // C/D: col = lane&15, row = (lane>>4)*4 + reg
                if (s < 7) pU[base + s * 192 + col] = uacc[it][rg];
            }
        }
    }

    // ---- pZ over 256 rows (wl intact)
    if (t < 112) {
        int s = t >> 4, part = t & 15;               // s = 0..6, 16 lanes each
        float z = 0.f;
        #pragma unroll
        for (int k = 0; k < 16; ++k) z += wl[(part + 16 * k) * 8 + s];
        #pragma unroll
        for (int o = 8; o > 0; o >>= 1) z += __shfl_xor(z, o);   // stays in 16-lane group
        if (part == 0) pZ[(bv * 16 + chunk) * 7 + s] = z;
    }
}

// ---------------------------------------------------------------- per-iter: GRU+MLP v5 — 16-chunk reduce, 4-way ILP
__global__ __launch_bounds__(576) void k_gru(
    const float* __restrict__ pU, const float* __restrict__ pZ, const float* __restrict__ full,
    const unsigned short* __restrict__ Wib, const unsigned short* __restrict__ Whb,
    const float* __restrict__ bi, const float* __restrict__ bh,
    const float* __restrict__ lng, const float* __restrict__ lnb,
    const unsigned short* __restrict__ W1b, const float* __restrict__ b1,
    const unsigned short* __restrict__ W2b, const float* __restrict__ b2,
    float* __restrict__ fnew)
{
    int row = blockIdx.x;                  // bv*7 + s
    int bv = row / 7, s = row % 7;
    int j = threadIdx.x;
    __shared__ float u[192], h[192], gi[576], gh[576], lnm[192], h1[256], red[8];

    // ---- phase 1: u (pU/Z reduce over 16 chunks, 4 independent chains) and h
    if (j < 192) {
        float u0 = 0.f, u1 = 0.f, u2 = 0.f, u3 = 0.f;
        #pragma unroll
        for (int c = 0; c < 16; c += 4) {
            u0 += pU[(((long)bv * 16 + c + 0) * 7 + s) * 192 + j];
            u1 += pU[(((long)bv * 16 + c + 1) * 7 + s) * 192 + j];
            u2 += pU[(((long)bv * 16 + c + 2) * 7 + s) * 192 + j];
            u3 += pU[(((long)bv * 16 + c + 3) * 7 + s) * 192 + j];
        }
        float z0 = 0.f, z1 = 0.f, z2 = 0.f, z3 = 0.f;
        #pragma unroll
        for (int c = 0; c < 16; c += 4) {
            z0 += pZ[(bv * 16 + c + 0) * 7 + s];
            z1 += pZ[(bv * 16 + c + 1) * 7 + s];
            z2 += pZ[(bv * 16 + c + 2) * 7 + s];
            z3 += pZ[(bv * 16 + c + 3) * 7 + s];
        }
        u[j] = ((u0 + u1) + (u2 + u3)) / ((z0 + z1) + (z2 + z3));
    } else if (j < 384) {
        int jj = j - 192;
        h[jj] = full[row * 192 + jj];
    }
    __syncthreads();

    // ---- phase 2: one gate column per thread, 4 partial chains per gate
    {
        float a0 = 0.f, a1 = 0.f, a2 = 0.f, a3 = 0.f;
        float b0 = 0.f, b1v = 0.f, b2v = 0.f, b3 = 0.f;
        #pragma unroll 4
        for (int k = 0; k < 192; k += 4) {
            float uk0 = u[k], uk1 = u[k + 1], uk2 = u[k + 2], uk3 = u[k + 3];
            float hk0 = h[k], hk1 = h[k + 1], hk2 = h[k + 2], hk3 = h[k + 3];
            a0  += uk0 * bf2f(Wib[(k + 0) * 576 + j]);
            a1  += uk1 * bf2f(Wib[(k + 1) * 576 + j]);
            a2  += uk2 * bf2f(Wib[(k + 2) * 576 + j]);
            a3  += uk3 * bf2f(Wib[(k + 3) * 576 + j]);
            b0  += hk0 * bf2f(Whb[(k + 0) * 576 + j]);
            b1v += hk1 * bf2f(Whb[(k + 1) * 576 + j]);
            b2v += hk2 * bf2f(Whb[(k + 2) * 576 + j]);
            b3  += hk3 * bf2f(Whb[(k + 3) * 576 + j]);
        }
        gi[j] = ((a0 + a1) + (a2 + a3)) + bi[j];
        gh[j] = ((b0 + b1v) + (b2v + b3)) + bh[j];
    }
    __syncthreads();

    // ---- phase 3: gates + GRU combine + LN (threads 0..191)
    float mn = 0.f;
    if (j < 192) {
        float hv = h[j];
        float r  = 1.f / (1.f + __expf(-(gi[j] + gh[j])));
        float z  = 1.f / (1.f + __expf(-(gi[192 + j] + gh[192 + j])));
        float nn = tanhf(gi[384 + j] + r * gh[384 + j]);
        mn = (1.f - z) * nn + z * hv;

        float s1 = mn, s2 = mn * mn;
        #pragma unroll
        for (int o = 32; o > 0; o >>= 1) { s1 += __shfl_xor(s1, o); s2 += __shfl_xor(s2, o); }
        int wave = j >> 6, lane = j & 63;
        if (lane == 0) { red[wave] = s1; red[4 + wave] = s2; }
    }
    __syncthreads();
    if (j < 192) {
        float ts = red[0] + red[1] + red[2], ts2 = red[4] + red[5] + red[6];
        float mean = ts * (1.f / 192.f);
        float var  = ts2 * (1.f / 192.f) - mean * mean;
        float rstd = rsqrtf(var + 1e-5f);
        lnm[j] = (mn - mean) * rstd * lng[j] + lnb[j];
    }
    __syncthreads();

    // ---- phase 4: MLP hidden (threads 0..255, 4 partial chains)
    if (j < 256) {
        float a0 = 0.f, a1 = 0.f, a2 = 0.f, a3 = 0.f;
        #pragma unroll 4
        for (int k = 0; k < 192; k += 4) {
            a0 += lnm[k + 0] * bf2f(W1b[(k + 0) * 256 + j]);
            a1 += lnm[k + 1] * bf2f(W1b[(k + 1) * 256 + j]);
            a2 += lnm[k + 2] * bf2f(W1b[(k + 2) * 256 + j]);
            a3 += lnm[k + 3] * bf2f(W1b[(k + 3) * 256 + j]);
        }
        h1[j] = fmaxf(((a0 + a1) + (a2 + a3)) + b1[j], 0.f);
    }
    __syncthreads();

    // ---- phase 5: MLP out + residual (threads 0..191, 4 partial chains)
    if (j < 192) {
        float a0 = 0.f, a1 = 0.f, a2 = 0.f, a3 = 0.f;
        #pragma unroll 4
        for (int c = 0; c < 256; c += 4) {
            a0 += h1[c + 0] * bf2f(W2b[(c + 0) * 192 + j]);
            a1 += h1[c + 1] * bf2f(W2b[(c + 1) * 192 + j]);
            a2 += h1[c + 2] * bf2f(W2b[(c + 2) * 192 + j]);
            a3 += h1[c + 3] * bf2f(W2b[(c + 3) * 192 + j]);
        }
        fnew[row * 192 + j] = mn + (((a0 + a1) + (a2 + a3)) + b2[j]);
    }
}

// ---------------------------------------------------------------- final: slot means -> d_out (r15 verbatim)
__global__ __launch_bounds__(256) void k_means(
    const float* __restrict__ fnew, float* __restrict__ oview, float* __restrict__ oattr)
{
    int t = blockIdx.x * 256 + threadIdx.x;
    if (t < 2048) {
        int bv = t >> 6, d = t & 63;
        float a = 0.f;
        #pragma unroll
        for (int s = 0; s < 7; ++s) a += fnew[(bv * 7 + s) * 192 + d];
        oview[t] = a * (1.f / 7.f);
    } else if (t < 9216) {
        int u = t - 2048;
        int b = u / 896, r = u % 896, s = r >> 7, d = r & 127;
        float a = 0.f;
        #pragma unroll
        for (int v = 0; v < 4; ++v) a += fnew[((b * 4 + v) * 7 + s) * 192 + 64 + d];
        oattr[u] = a * 0.25f;
    }
}

// ---------------------------------------------------------------- host
extern "C" void kernel_launch(void* const* d_in, const int* in_sizes, int n_in,
                              void* d_out, int out_size, void* d_ws, size_t ws_size,
                              hipStream_t stream)
{
    const float* x          = (const float*)d_in[0];
    const float* noise_view = (const float*)d_in[1];
    const float* noise_obj  = (const float*)d_in[2];
    const float* noise_bck  = (const float*)d_in[3];
    const float* ln_in_g    = (const float*)d_in[4];
    const float* ln_in_b    = (const float*)d_in[5];
    const float* ln_qry_g   = (const float*)d_in[6];
    const float* ln_qry_b   = (const float*)d_in[7];
    const float* ln_res_g   = (const float*)d_in[8];
    const float* ln_res_b   = (const float*)d_in[9];
    const float* view_loc   = (const float*)d_in[10];
    const float* view_lscl  = (const float*)d_in[11];
    const float* ao_loc     = (const float*)d_in[12];
    const float* ao_scl     = (const float*)d_in[13];
    const float* ab_loc     = (const float*)d_in[14];
    const float* ab_scl     = (const float*)d_in[15];
    const float* W_qry      = (const float*)d_in[16];
    const float* W_key      = (const float*)d_in[17];
    const float* W_val      = (const float*)d_in[18];
    const float* gru_Wi     = (const float*)d_in[19];
    const float* gru_Wh     = (const float*)d_in[20];
    const float* gru_bi     = (const float*)d_in[21];
    const float* gru_bh     = (const float*)d_in[22];
    const float* mlp_W1     = (const float*)d_in[23];
    const float* mlp_b1     = (const float*)d_in[24];
    const float* mlp_W2     = (const float*)d_in[25];
    const float* mlp_b2     = (const float*)d_in[26];

    char* ws = (char*)d_ws;
    size_t off = 0;
    auto alloc = [&](size_t bytes) { void* p = ws + off; off += (bytes + 255) & ~255ULL; return p; };
    unsigned short* xkv = (unsigned short*)alloc(131072UL * 320 * 2);   // 80 MB
    unsigned short* Wt  = (unsigned short*)alloc(320UL * 256 * 2);
    unsigned short* qbf = (unsigned short*)alloc(32UL * 16 * 128 * 2);
    float* pU    = (float*)alloc(32UL * 16 * 7 * 192 * 4);              // 2.75 MB
    float* pZ    = (float*)alloc(32UL * 16 * 7 * 4);
    float* fullb = (float*)alloc(224UL * 192 * 4);
    float* fnew  = (float*)alloc(224UL * 192 * 4);
    float* sview = (float*)alloc(2048UL * 4);
    float* sattr = (float*)alloc(7168UL * 4);
    unsigned short* Wib = (unsigned short*)alloc(110592UL * 2);
    unsigned short* Whb = (unsigned short*)alloc(110592UL * 2);
    unsigned short* W1b = (unsigned short*)alloc(49152UL * 2);
    unsigned short* W2b = (unsigned short*)alloc(49152UL * 2);

    k_prep<<<dim3(672), dim3(256), 0, stream>>>(
        W_key, W_val, view_loc, view_lscl, noise_view,
        ao_loc, ao_scl, noise_obj, ab_loc, ab_scl, noise_bck,
        gru_Wi, gru_Wh, mlp_W1, mlp_W2,
        Wt, qbf, sview, sattr, Wib, Whb, W1b, W2b);
    k_lnkv<<<dim3(2048), dim3(256), 0, stream>>>(x, ln_in_g, ln_in_b, Wt, xkv);

    for (int it = 0; it < 3; ++it) {
        k_qry<<<dim3(224), dim3(384), 0, stream>>>(sview, sattr, fnew, (it > 0) ? 1 : 0,
                                                   ln_qry_g, ln_qry_b, W_qry, fullb, qbf);
        k_attu<<<dim3(512), dim3(256), 0, stream>>>(qbf, xkv, pU, pZ);
        k_gru<<<dim3(224), dim3(576), 0, stream>>>(pU, pZ, fullb, Wib, Whb, gru_bi, gru_bh,
                                                   ln_res_g, ln_res_b, W1b, mlp_b1, W2b, mlp_b2, fnew);
    }
    k_means<<<dim3(36), dim3(256), 0, stream>>>(fnew, (float*)d_out, ((float*)d_out) + 2048);
}

// Round 18
// 203.250 us; speedup vs baseline: 1.1953x; 1.0213x over previous
//
#include <hip/hip_runtime.h>
#include <cstdint>
#include <cstddef>

// ---------------------------------------------------------------- types
typedef float  f32x4 __attribute__((ext_vector_type(4)));
typedef short  s16x8 __attribute__((ext_vector_type(8)));
typedef __bf16 bf16x8 __attribute__((ext_vector_type(8)));

static __device__ __forceinline__ f32x4 mfma16(s16x8 a, s16x8 b, f32x4 c) {
    return __builtin_amdgcn_mfma_f32_16x16x32_bf16(
        __builtin_bit_cast(bf16x8, a), __builtin_bit_cast(bf16x8, b), c, 0, 0, 0);
}

static __device__ __forceinline__ unsigned short f2bf(float f) {
    unsigned int u = __builtin_bit_cast(unsigned int, f);
    u = (u + 0x7fffu + ((u >> 16) & 1u)) >> 16;
    return (unsigned short)u;
}
static __device__ __forceinline__ float bf2f(unsigned short h) {
    unsigned int u = ((unsigned int)h) << 16;
    return __builtin_bit_cast(float, u);
}

#define COEF 0.08838834764831845f

// ---------------------------------------------------------------- prep v3: weights packed k-interleaved-by-4
// W4[kq][j][i] = bf16(W[(4kq+i)][j]); one uint2 load yields 4 k-slices of column j.
__global__ __launch_bounds__(256) void k_prep(
    const float* __restrict__ Wkey, const float* __restrict__ Wval,
    const float* __restrict__ vloc, const float* __restrict__ vlscl, const float* __restrict__ nview,
    const float* __restrict__ aoloc, const float* __restrict__ aoscl, const float* __restrict__ nobj,
    const float* __restrict__ abloc, const float* __restrict__ abscl, const float* __restrict__ nbck,
    const float* __restrict__ Wi, const float* __restrict__ Wh,
    const float* __restrict__ W1, const float* __restrict__ W2,
    unsigned short* __restrict__ Wt, unsigned short* __restrict__ qbf,
    float* __restrict__ sview, float* __restrict__ sattr,
    unsigned short* __restrict__ Wib, unsigned short* __restrict__ Whb,
    unsigned short* __restrict__ W1b, unsigned short* __restrict__ W2b)
{
    int blk = blockIdx.x, t = threadIdx.x;
    if (blk < 320) {
        float v = (blk < 128) ? Wkey[t * 128 + blk] : Wval[t * 192 + (blk - 128)];
        Wt[blk * 256 + t] = f2bf(v);
    } else if (blk < 356) {
        int g = (blk - 320) * 256 + t;
        if (g < 2048) {
            int d = g & 63;
            sview[g] = vloc[d] + __expf(vlscl[d]) * nview[g];
        } else {
            int u = g - 2048;               // [b][s][128]
            int b = u / 896, r = u % 896, s = r >> 7, d = r & 127;
            float val;
            if (s < 6) val = aoloc[d] + __expf(aoscl[d]) * nobj[(b * 6 + s) * 128 + d];
            else       val = abloc[d] + __expf(abscl[d]) * nbck[b * 128 + d];
            sattr[u] = val;
        }
    } else if (blk < 360) {
        for (int e = (blk - 356) * 256 + t; e < 32 * 9 * 128; e += 1024) {
            int bv = e / 1152, r = e % 1152, s = 7 + r / 128, k = r & 127;
            qbf[(bv * 16 + s) * 128 + k] = 0;
        }
    } else if (blk < 468) {                // Wib4: 27648 threads
        int g = (blk - 360) * 256 + t;
        int j = g % 576, kq = g / 576;
        unsigned s0 = f2bf(Wi[(kq * 4 + 0) * 576 + j]);
        unsigned s1 = f2bf(Wi[(kq * 4 + 1) * 576 + j]);
        unsigned s2 = f2bf(Wi[(kq * 4 + 2) * 576 + j]);
        unsigned s3 = f2bf(Wi[(kq * 4 + 3) * 576 + j]);
        *(uint2*)(Wib + kq * 2304 + j * 4) = make_uint2(s0 | (s1 << 16), s2 | (s3 << 16));
    } else if (blk < 576) {                // Whb4
        int g = (blk - 468) * 256 + t;
        int j = g % 576, kq = g / 576;
        unsigned s0 = f2bf(Wh[(kq * 4 + 0) * 576 + j]);
        unsigned s1 = f2bf(Wh[(kq * 4 + 1) * 576 + j]);
        unsigned s2 = f2bf(Wh[(kq * 4 + 2) * 576 + j]);
        unsigned s3 = f2bf(Wh[(kq * 4 + 3) * 576 + j]);
        *(uint2*)(Whb + kq * 2304 + j * 4) = make_uint2(s0 | (s1 << 16), s2 | (s3 << 16));
    } else if (blk < 624) {                // W1b4: 12288 threads
        int g = (blk - 576) * 256 + t;
        int j = g % 256, kq = g / 256;
        unsigned s0 = f2bf(W1[(kq * 4 + 0) * 256 + j]);
        unsigned s1 = f2bf(W1[(kq * 4 + 1) * 256 + j]);
        unsigned s2 = f2bf(W1[(kq * 4 + 2) * 256 + j]);
        unsigned s3 = f2bf(W1[(kq * 4 + 3) * 256 + j]);
        *(uint2*)(W1b + kq * 1024 + j * 4) = make_uint2(s0 | (s1 << 16), s2 | (s3 << 16));
    } else {                               // W2b4: 12288 threads
        int g = (blk - 624) * 256 + t;
        int j = g % 192, kq = g / 192;     // kq 0..63
        unsigned s0 = f2bf(W2[(kq * 4 + 0) * 192 + j]);
        unsigned s1 = f2bf(W2[(kq * 4 + 1) * 192 + j]);
        unsigned s2 = f2bf(W2[(kq * 4 + 2) * 192 + j]);
        unsigned s3 = f2bf(W2[(kq * 4 + 3) * 192 + j]);
        *(uint2*)(W2b + kq * 768 + j * 4) = make_uint2(s0 | (s1 << 16), s2 | (s3 << 16));
    }
}

// ---------------------------------------------------------------- phase A (round-1 verbatim, measured 110.8 us — FROZEN)
__global__ __launch_bounds__(256) void k_lnkv(
    const float* __restrict__ x, const float* __restrict__ lng, const float* __restrict__ lnb,
    const unsigned short* __restrict__ Wt, unsigned short* __restrict__ xkv)
{
    __shared__ unsigned short lds[64 * 320];        // 40 KB
    const int t = threadIdx.x, wave = t >> 6, lane = t & 63;
    const int l15 = lane & 15, lg = lane >> 4;
    const long rowbase = (long)blockIdx.x * 64;

    float4 gv = *(const float4*)(lng + lane * 4);
    float4 bv = *(const float4*)(lnb + lane * 4);
    for (int r = 0; r < 16; ++r) {
        int row = wave * 16 + r;
        float4 xv = *(const float4*)(x + (rowbase + row) * 256 + lane * 4);
        float s1 = xv.x + xv.y + xv.z + xv.w;
        float s2 = xv.x * xv.x + xv.y * xv.y + xv.z * xv.z + xv.w * xv.w;
        #pragma unroll
        for (int o = 32; o > 0; o >>= 1) { s1 += __shfl_xor(s1, o); s2 += __shfl_xor(s2, o); }
        float mean = s1 * (1.f / 256.f);
        float var  = s2 * (1.f / 256.f) - mean * mean;
        float rstd = rsqrtf(var + 1e-5f);
        float y0 = (xv.x - mean) * rstd * gv.x + bv.x;
        float y1 = (xv.y - mean) * rstd * gv.y + bv.y;
        float y2 = (xv.z - mean) * rstd * gv.z + bv.z;
        float y3 = (xv.w - mean) * rstd * gv.w + bv.w;
        unsigned int u0 = (unsigned)f2bf(y0) | ((unsigned)f2bf(y1) << 16);
        unsigned int u1 = (unsigned)f2bf(y2) | ((unsigned)f2bf(y3) << 16);
        int off = row * 512 + ((lane * 8) ^ ((row & 7) << 4));
        *(uint2*)((char*)lds + off) = make_uint2(u0, u1);
    }
    __syncthreads();

    f32x4 acc[4][5];
    #pragma unroll
    for (int mt = 0; mt < 4; ++mt)
        #pragma unroll
        for (int nt = 0; nt < 5; ++nt) acc[mt][nt] = (f32x4){0.f, 0.f, 0.f, 0.f};

    const int nb = wave * 80;
    #pragma unroll
    for (int kk = 0; kk < 8; ++kk) {
        s16x8 a[4], b[5];
        #pragma unroll
        for (int mt = 0; mt < 4; ++mt) {
            int row = mt * 16 + l15;
            int off = row * 512 + ((kk * 64 + lg * 16) ^ ((row & 7) << 4));
            a[mt] = *(const s16x8*)((char*)lds + off);
        }
        #pragma unroll
        for (int nt = 0; nt < 5; ++nt) {
            int col = nb + nt * 16 + l15;
            b[nt] = *(const s16x8*)(Wt + col * 256 + kk * 32 + lg * 8);
        }
        #pragma unroll
        for (int mt = 0; mt < 4; ++mt)
            #pragma unroll
            for (int nt = 0; nt < 5; ++nt)
                acc[mt][nt] = mfma16(a[mt], b[nt], acc[mt][nt]);
    }
    __syncthreads();

    #pragma unroll
    for (int mt = 0; mt < 4; ++mt)
        #pragma unroll
        for (int nt = 0; nt < 5; ++nt)
            #pragma unroll
            for (int rg = 0; rg < 4; ++rg) {
                int row = mt * 16 + lg * 4 + rg;
                int col = nb + nt * 16 + l15;
                lds[row * 320 + col] = f2bf(acc[mt][nt][rg]);
            }
    __syncthreads();
    const uint4* src = (const uint4*)lds;
    uint4* dst = (uint4*)(xkv + rowbase * 320);
    #pragma unroll
    for (int j = 0; j < 10; ++j) dst[j * 256 + t] = src[j * 256 + t];
}

// ---------------------------------------------------------------- per-iter: q v3 (r17 verbatim)
__global__ __launch_bounds__(384) void k_qry(
    const float* __restrict__ sview, const float* __restrict__ sattr,
    const float* __restrict__ fnewp, int use_fnew,
    const float* __restrict__ lng, const float* __restrict__ lnb,
    const float* __restrict__ Wq, float* __restrict__ full, unsigned short* __restrict__ qbf)
{
    int row = blockIdx.x;                  // bv*7 + s
    int bv = row / 7, s = row % 7, b = bv >> 2;
    int j = threadIdx.x;
    __shared__ float fr[192];
    __shared__ float part[384];
    __shared__ float red[8];
    float v = 0.f;
    if (j < 192) {
        if (use_fnew) {
            if (j < 64) {
                float a = 0.f;
                #pragma unroll
                for (int sp = 0; sp < 7; ++sp) a += fnewp[(bv * 7 + sp) * 192 + j];
                v = a * (1.f / 7.f);
            } else {
                float a = 0.f;
                #pragma unroll
                for (int vv = 0; vv < 4; ++vv) a += fnewp[((b * 4 + vv) * 7 + s) * 192 + j];
                v = a * 0.25f;
            }
        } else {
            v = (j < 64) ? sview[bv * 64 + j] : sattr[(b * 7 + s) * 128 + (j - 64)];
        }
        full[row * 192 + j] = v;
        float s1 = v, s2 = v * v;
        #pragma unroll
        for (int o = 32; o > 0; o >>= 1) { s1 += __shfl_xor(s1, o); s2 += __shfl_xor(s2, o); }
        int wave = j >> 6, lane = j & 63;
        if (lane == 0) { red[wave] = s1; red[4 + wave] = s2; }
    }
    __syncthreads();
    if (j < 192) {
        float ts = red[0] + red[1] + red[2], ts2 = red[4] + red[5] + red[6];
        float mean = ts * (1.f / 192.f);
        float var  = ts2 * (1.f / 192.f) - mean * mean;
        float rstd = rsqrtf(var + 1e-5f);
        fr[j] = (v - mean) * rstd * lng[j] + lnb[j];
    }
    __syncthreads();
    {
        int c = j & 127, seg = j >> 7;               // 3 segments x 64 k
        float acc = 0.f;
        #pragma unroll
        for (int k = 0; k < 64; ++k) acc += fr[seg * 64 + k] * Wq[(seg * 64 + k) * 128 + c];
        part[j] = acc;
    }
    __syncthreads();
    if (j < 128) {
        float acc = part[j] + part[128 + j] + part[256 + j];
        qbf[(bv * 16 + s) * 128 + j] = f2bf(acc * COEF);
    }
}

// ---------------------------------------------------------------- per-iter: fused attn+upd v3 (r17 verbatim)
__global__ __launch_bounds__(256) void k_attu(
    const unsigned short* __restrict__ qbf, const unsigned short* __restrict__ xkv,
    float* __restrict__ pU, float* __restrict__ pZ)
{
    int blk = blockIdx.x;                  // 512 = 32 bv * 16 chunks(256 n)
    int bv = blk >> 4, chunk = blk & 15;
    int n0 = chunk * 256;
    int t = threadIdx.x, wave = t >> 6, lane = t & 63;
    int l15 = lane & 15, lg = lane >> 4;
    __shared__ float wl[256 * 8];

    s16x8 aq[4];
    const unsigned short* qrow = qbf + (bv * 16 + l15) * 128 + lg * 8;
    #pragma unroll
    for (int kk = 0; kk < 4; ++kk) aq[kk] = *(const s16x8*)(qrow + kk * 32);

    #pragma unroll
    for (int batch = 0; batch < 4; ++batch) {
        int nloc = batch * 64 + wave * 16;
        const unsigned short* xr = xkv + ((long)(bv * 4096 + n0 + nloc + l15)) * 320 + lg * 8;
        f32x4 acc = (f32x4){0.f, 0.f, 0.f, 0.f};
        #pragma unroll
        for (int kk = 0; kk < 4; ++kk) {
            s16x8 bfr = *(const s16x8*)(xr + kk * 32);
            acc = mfma16(aq[kk], bfr, acc);
        }
        float o0 = __shfl_xor(acc[0], 16), o1 = __shfl_xor(acc[1], 16);
        float o2 = __shfl_xor(acc[2], 16), o3 = __shfl_xor(acc[3], 16);
        bool hi = (lg & 1);
        float v0 = hi ? o0 : acc[0], v1 = hi ? o1 : acc[1];
        float v2 = hi ? o2 : acc[2], v3 = hi ? o3 : acc[3];
        float v4 = hi ? acc[0] : o0, v5 = hi ? acc[1] : o1, v6 = hi ? acc[2] : o2;
        float m = fmaxf(fmaxf(fmaxf(v0, v1), fmaxf(v2, v3)), fmaxf(fmaxf(v4, v5), v6));
        float e0 = __expf(v0 - m), e1 = __expf(v1 - m), e2 = __expf(v2 - m), e3 = __expf(v3 - m);
        float e4 = __expf(v4 - m), e5 = __expf(v5 - m), e6 = __expf(v6 - m);
        float inv = 1.f / (e0 + e1 + e2 + e3 + e4 + e5 + e6);
        if (lg < 2) {
            int n = nloc + l15;                // LOCAL row index 0..255
            float4 out = (lg == 0) ? make_float4(e0 * inv, e1 * inv, e2 * inv, e3 * inv)
                                   : make_float4(e4 * inv, e5 * inv, e6 * inv, 0.f);
            *(float4*)(wl + n * 8 + lg * 4) = out;
        }
    }
    __syncthreads();

    {
        f32x4 uacc[3];
        #pragma unroll
        for (int it = 0; it < 3; ++it) uacc[it] = (f32x4){0.f, 0.f, 0.f, 0.f};
        const unsigned short* vbase = xkv + ((long)(bv * 4096 + n0)) * 320 + 128;

        #pragma unroll
        for (int kb = 0; kb < 8; ++kb) {
            s16x8 aw = (s16x8){0, 0, 0, 0, 0, 0, 0, 0};
            if (l15 < 8) {
                #pragma unroll
                for (int j2 = 0; j2 < 8; ++j2)
                    aw[j2] = (short)f2bf(wl[(kb * 32 + lg * 8 + j2) * 8 + l15]);
            }
            #pragma unroll
            for (int it = 0; it < 3; ++it) {
                int col = wave * 48 + it * 16 + l15;
                s16x8 bw;
                #pragma unroll
                for (int j2 = 0; j2 < 8; ++j2)
                    bw[j2] = (short)vbase[(long)(kb * 32 + lg * 8 + j2) * 320 + col];
                uacc[it] = mfma16(aw, bw, uacc[it]);
            }
        }

        long base = (((long)bv * 16 + chunk) * 7) * 192;
        #pragma unroll
        for (int it = 0; it < 3; ++it) {
            int col = wave * 48 + it * 16 + l15;
            #pragma unroll
            for (int rg = 0; rg < 4; ++rg) {
                int s = lg * 4 + rg;
                if (s < 7) pU[base + s * 192 + col] = uacc[it][rg];
            }
        }
    }

    if (t < 112) {
        int s = t >> 4, part = t & 15;
        float z = 0.f;
        #pragma unroll
        for (int k = 0; k < 16; ++k) z += wl[(part + 16 * k) * 8 + s];
        #pragma unroll
        for (int o = 8; o > 0; o >>= 1) z += __shfl_xor(z, o);
        if (part == 0) pZ[(bv * 16 + chunk) * 7 + s] = z;
    }
}

// ---------------------------------------------------------------- per-iter: GRU+MLP v6 — packed uint2 weight loads
__global__ __launch_bounds__(576) void k_gru(
    const float* __restrict__ pU, const float* __restrict__ pZ, const float* __restrict__ full,
    const unsigned short* __restrict__ Wib, const unsigned short* __restrict__ Whb,
    const float* __restrict__ bi, const float* __restrict__ bh,
    const float* __restrict__ lng, const float* __restrict__ lnb,
    const unsigned short* __restrict__ W1b, const float* __restrict__ b1,
    const unsigned short* __restrict__ W2b, const float* __restrict__ b2,
    float* __restrict__ fnew)
{
    int row = blockIdx.x;                  // bv*7 + s
    int bv = row / 7, s = row % 7;
    int j = threadIdx.x;
    __shared__ float u[192], h[192], gi[576], gh[576], lnm[192], h1[256], red[8];

    // ---- phase 1: u (pU/Z reduce over 16 chunks, 4 chains) and h
    if (j < 192) {
        float u0 = 0.f, u1 = 0.f, u2 = 0.f, u3 = 0.f;
        #pragma unroll
        for (int c = 0; c < 16; c += 4) {
            u0 += pU[(((long)bv * 16 + c + 0) * 7 + s) * 192 + j];
            u1 += pU[(((long)bv * 16 + c + 1) * 7 + s) * 192 + j];
            u2 += pU[(((long)bv * 16 + c + 2) * 7 + s) * 192 + j];
            u3 += pU[(((long)bv * 16 + c + 3) * 7 + s) * 192 + j];
        }
        float z0 = 0.f, z1 = 0.f, z2 = 0.f, z3 = 0.f;
        #pragma unroll
        for (int c = 0; c < 16; c += 4) {
            z0 += pZ[(bv * 16 + c + 0) * 7 + s];
            z1 += pZ[(bv * 16 + c + 1) * 7 + s];
            z2 += pZ[(bv * 16 + c + 2) * 7 + s];
            z3 += pZ[(bv * 16 + c + 3) * 7 + s];
        }
        u[j] = ((u0 + u1) + (u2 + u3)) / ((z0 + z1) + (z2 + z3));
    } else if (j < 384) {
        int jj = j - 192;
        h[jj] = full[row * 192 + jj];
    }
    __syncthreads();

    // ---- phase 2: gate column per thread; uint2 packed weights (4 k / load)
    {
        float a0 = 0.f, a1 = 0.f, a2 = 0.f, a3 = 0.f;
        float b0 = 0.f, b1v = 0.f, b2v = 0.f, b3 = 0.f;
        #pragma unroll 4
        for (int kq = 0; kq < 48; ++kq) {
            uint2 wi = *(const uint2*)(Wib + kq * 2304 + j * 4);
            uint2 wh = *(const uint2*)(Whb + kq * 2304 + j * 4);
            int k = kq * 4;
            a0  += u[k + 0] * bf2f((unsigned short)(wi.x & 0xffffu));
            a1  += u[k + 1] * bf2f((unsigned short)(wi.x >> 16));
            a2  += u[k + 2] * bf2f((unsigned short)(wi.y & 0xffffu));
            a3  += u[k + 3] * bf2f((unsigned short)(wi.y >> 16));
            b0  += h[k + 0] * bf2f((unsigned short)(wh.x & 0xffffu));
            b1v += h[k + 1] * bf2f((unsigned short)(wh.x >> 16));
            b2v += h[k + 2] * bf2f((unsigned short)(wh.y & 0xffffu));
            b3  += h[k + 3] * bf2f((unsigned short)(wh.y >> 16));
        }
        gi[j] = ((a0 + a1) + (a2 + a3)) + bi[j];
        gh[j] = ((b0 + b1v) + (b2v + b3)) + bh[j];
    }
    __syncthreads();

    // ---- phase 3: gates + GRU combine + LN (threads 0..191)
    float mn = 0.f;
    if (j < 192) {
        float hv = h[j];
        float r  = 1.f / (1.f + __expf(-(gi[j] + gh[j])));
        float z  = 1.f / (1.f + __expf(-(gi[192 + j] + gh[192 + j])));
        float nn = tanhf(gi[384 + j] + r * gh[384 + j]);
        mn = (1.f - z) * nn + z * hv;

        float s1 = mn, s2 = mn * mn;
        #pragma unroll
        for (int o = 32; o > 0; o >>= 1) { s1 += __shfl_xor(s1, o); s2 += __shfl_xor(s2, o); }
        int wave = j >> 6, lane = j & 63;
        if (lane == 0) { red[wave] = s1; red[4 + wave] = s2; }
    }
    __syncthreads();
    if (j < 192) {
        float ts = red[0] + red[1] + red[2], ts2 = red[4] + red[5] + red[6];
        float mean = ts * (1.f / 192.f);
        float var  = ts2 * (1.f / 192.f) - mean * mean;
        float rstd = rsqrtf(var + 1e-5f);
        lnm[j] = (mn - mean) * rstd * lng[j] + lnb[j];
    }
    __syncthreads();

    // ---- phase 4: MLP hidden (threads 0..255; packed loads)
    if (j < 256) {
        float a0 = 0.f, a1 = 0.f, a2 = 0.f, a3 = 0.f;
        #pragma unroll 4
        for (int kq = 0; kq < 48; ++kq) {
            uint2 w1 = *(const uint2*)(W1b + kq * 1024 + j * 4);
            int k = kq * 4;
            a0 += lnm[k + 0] * bf2f((unsigned short)(w1.x & 0xffffu));
            a1 += lnm[k + 1] * bf2f((unsigned short)(w1.x >> 16));
            a2 += lnm[k + 2] * bf2f((unsigned short)(w1.y & 0xffffu));
            a3 += lnm[k + 3] * bf2f((unsigned short)(w1.y >> 16));
        }
        h1[j] = fmaxf(((a0 + a1) + (a2 + a3)) + b1[j], 0.f);
    }
    __syncthreads();

    // ---- phase 5: MLP out + residual (threads 0..191; packed loads)
    if (j < 192) {
        float a0 = 0.f, a1 = 0.f, a2 = 0.f, a3 = 0.f;
        #pragma unroll 4
        for (int cq = 0; cq < 64; ++cq) {
            uint2 w2 = *(const uint2*)(W2b + cq * 768 + j * 4);
            int c = cq * 4;
            a0 += h1[c + 0] * bf2f((unsigned short)(w2.x & 0xffffu));
            a1 += h1[c + 1] * bf2f((unsigned short)(w2.x >> 16));
            a2 += h1[c + 2] * bf2f((unsigned short)(w2.y & 0xffffu));
            a3 += h1[c + 3] * bf2f((unsigned short)(w2.y >> 16));
        }
        fnew[row * 192 + j] = mn + (((a0 + a1) + (a2 + a3)) + b2[j]);
    }
}

// ---------------------------------------------------------------- final: slot means -> d_out (r17 verbatim)
__global__ __launch_bounds__(256) void k_means(
    const float* __restrict__ fnew, float* __restrict__ oview, float* __restrict__ oattr)
{
    int t = blockIdx.x * 256 + threadIdx.x;
    if (t < 2048) {
        int bv = t >> 6, d = t & 63;
        float a = 0.f;
        #pragma unroll
        for (int s = 0; s < 7; ++s) a += fnew[(bv * 7 + s) * 192 + d];
        oview[t] = a * (1.f / 7.f);
    } else if (t < 9216) {
        int u = t - 2048;
        int b = u / 896, r = u % 896, s = r >> 7, d = r & 127;
        float a = 0.f;
        #pragma unroll
        for (int v = 0; v < 4; ++v) a += fnew[((b * 4 + v) * 7 + s) * 192 + 64 + d];
        oattr[u] = a * 0.25f;
    }
}

// ---------------------------------------------------------------- host
extern "C" void kernel_launch(void* const* d_in, const int* in_sizes, int n_in,
                              void* d_out, int out_size, void* d_ws, size_t ws_size,
                              hipStream_t stream)
{
    const float* x          = (const float*)d_in[0];
    const float* noise_view = (const float*)d_in[1];
    const float* noise_obj  = (const float*)d_in[2];
    const float* noise_bck  = (const float*)d_in[3];
    const float* ln_in_g    = (const float*)d_in[4];
    const float* ln_in_b    = (const float*)d_in[5];
    const float* ln_qry_g   = (const float*)d_in[6];
    const float* ln_qry_b   = (const float*)d_in[7];
    const float* ln_res_g   = (const float*)d_in[8];
    const float* ln_res_b   = (const float*)d_in[9];
    const float* view_loc   = (const float*)d_in[10];
    const float* view_lscl  = (const float*)d_in[11];
    const float* ao_loc     = (const float*)d_in[12];
    const float* ao_scl     = (const float*)d_in[13];
    const float* ab_loc     = (const float*)d_in[14];
    const float* ab_scl     = (const float*)d_in[15];
    const float* W_qry      = (const float*)d_in[16];
    const float* W_key      = (const float*)d_in[17];
    const float* W_val      = (const float*)d_in[18];
    const float* gru_Wi     = (const float*)d_in[19];
    const float* gru_Wh     = (const float*)d_in[20];
    const float* gru_bi     = (const float*)d_in[21];
    const float* gru_bh     = (const float*)d_in[22];
    const float* mlp_W1     = (const float*)d_in[23];
    const float* mlp_b1     = (const float*)d_in[24];
    const float* mlp_W2     = (const float*)d_in[25];
    const float* mlp_b2     = (const float*)d_in[26];

    char* ws = (char*)d_ws;
    size_t off = 0;
    auto alloc = [&](size_t bytes) { void* p = ws + off; off += (bytes + 255) & ~255ULL; return p; };
    unsigned short* xkv = (unsigned short*)alloc(131072UL * 320 * 2);   // 80 MB
    unsigned short* Wt  = (unsigned short*)alloc(320UL * 256 * 2);
    unsigned short* qbf = (unsigned short*)alloc(32UL * 16 * 128 * 2);
    float* pU    = (float*)alloc(32UL * 16 * 7 * 192 * 4);              // 2.75 MB
    float* pZ    = (float*)alloc(32UL * 16 * 7 * 4);
    float* fullb = (float*)alloc(224UL * 192 * 4);
    float* fnew  = (float*)alloc(224UL * 192 * 4);
    float* sview = (float*)alloc(2048UL * 4);
    float* sattr = (float*)alloc(7168UL * 4);
    unsigned short* Wib = (unsigned short*)alloc(110592UL * 2);
    unsigned short* Whb = (unsigned short*)alloc(110592UL * 2);
    unsigned short* W1b = (unsigned short*)alloc(49152UL * 2);
    unsigned short* W2b = (unsigned short*)alloc(49152UL * 2);

    k_prep<<<dim3(672), dim3(256), 0, stream>>>(
        W_key, W_val, view_loc, view_lscl, noise_view,
        ao_loc, ao_scl, noise_obj, ab_loc, ab_scl, noise_bck,
        gru_Wi, gru_Wh, mlp_W1, mlp_W2,
        Wt, qbf, sview, sattr, Wib, Whb, W1b, W2b);
    k_lnkv<<<dim3(2048), dim3(256), 0, stream>>>(x, ln_in_g, ln_in_b, Wt, xkv);

    for (int it = 0; it < 3; ++it) {
        k_qry<<<dim3(224), dim3(384), 0, stream>>>(sview, sattr, fnew, (it > 0) ? 1 : 0,
                                                   ln_qry_g, ln_qry_b, W_qry, fullb, qbf);
        k_attu<<<dim3(512), dim3(256), 0, stream>>>(qbf, xkv, pU, pZ);
        k_gru<<<dim3(224), dim3(576), 0, stream>>>(pU, pZ, fullb, Wib, Whb, gru_bi, gru_bh,
                                                   ln_res_g, ln_res_b, W1b, mlp_b1, W2b, mlp_b2, fnew);
    }
    k_means<<<dim3(36), dim3(256), 0, stream>>>(fnew, (float*)d_out, ((float*)d_out) + 2048);
}

// Round 19
// 200.224 us; speedup vs baseline: 1.2134x; 1.0151x over previous
//
#include <hip/hip_runtime.h>
#include <cstdint>
#include <cstddef>

// ---------------------------------------------------------------- types
typedef float  f32x4 __attribute__((ext_vector_type(4)));
typedef short  s16x8 __attribute__((ext_vector_type(8)));
typedef __bf16 bf16x8 __attribute__((ext_vector_type(8)));

static __device__ __forceinline__ f32x4 mfma16(s16x8 a, s16x8 b, f32x4 c) {
    return __builtin_amdgcn_mfma_f32_16x16x32_bf16(
        __builtin_bit_cast(bf16x8, a), __builtin_bit_cast(bf16x8, b), c, 0, 0, 0);
}

static __device__ __forceinline__ unsigned short f2bf(float f) {
    unsigned int u = __builtin_bit_cast(unsigned int, f);
    u = (u + 0x7fffu + ((u >> 16) & 1u)) >> 16;
    return (unsigned short)u;
}
static __device__ __forceinline__ float bf2f(unsigned short h) {
    unsigned int u = ((unsigned int)h) << 16;
    return __builtin_bit_cast(float, u);
}

#define COEF 0.08838834764831845f

// ---------------------------------------------------------------- prep v3 (r18 verbatim)
__global__ __launch_bounds__(256) void k_prep(
    const float* __restrict__ Wkey, const float* __restrict__ Wval,
    const float* __restrict__ vloc, const float* __restrict__ vlscl, const float* __restrict__ nview,
    const float* __restrict__ aoloc, const float* __restrict__ aoscl, const float* __restrict__ nobj,
    const float* __restrict__ abloc, const float* __restrict__ abscl, const float* __restrict__ nbck,
    const float* __restrict__ Wi, const float* __restrict__ Wh,
    const float* __restrict__ W1, const float* __restrict__ W2,
    unsigned short* __restrict__ Wt, unsigned short* __restrict__ qbf,
    float* __restrict__ sview, float* __restrict__ sattr,
    unsigned short* __restrict__ Wib, unsigned short* __restrict__ Whb,
    unsigned short* __restrict__ W1b, unsigned short* __restrict__ W2b)
{
    int blk = blockIdx.x, t = threadIdx.x;
    if (blk < 320) {
        float v = (blk < 128) ? Wkey[t * 128 + blk] : Wval[t * 192 + (blk - 128)];
        Wt[blk * 256 + t] = f2bf(v);
    } else if (blk < 356) {
        int g = (blk - 320) * 256 + t;
        if (g < 2048) {
            int d = g & 63;
            sview[g] = vloc[d] + __expf(vlscl[d]) * nview[g];
        } else {
            int u = g - 2048;               // [b][s][128]
            int b = u / 896, r = u % 896, s = r >> 7, d = r & 127;
            float val;
            if (s < 6) val = aoloc[d] + __expf(aoscl[d]) * nobj[(b * 6 + s) * 128 + d];
            else       val = abloc[d] + __expf(abscl[d]) * nbck[b * 128 + d];
            sattr[u] = val;
        }
    } else if (blk < 360) {
        for (int e = (blk - 356) * 256 + t; e < 32 * 9 * 128; e += 1024) {
            int bv = e / 1152, r = e % 1152, s = 7 + r / 128, k = r & 127;
            qbf[(bv * 16 + s) * 128 + k] = 0;
        }
    } else if (blk < 468) {                // Wib4
        int g = (blk - 360) * 256 + t;
        int j = g % 576, kq = g / 576;
        unsigned s0 = f2bf(Wi[(kq * 4 + 0) * 576 + j]);
        unsigned s1 = f2bf(Wi[(kq * 4 + 1) * 576 + j]);
        unsigned s2 = f2bf(Wi[(kq * 4 + 2) * 576 + j]);
        unsigned s3 = f2bf(Wi[(kq * 4 + 3) * 576 + j]);
        *(uint2*)(Wib + kq * 2304 + j * 4) = make_uint2(s0 | (s1 << 16), s2 | (s3 << 16));
    } else if (blk < 576) {                // Whb4
        int g = (blk - 468) * 256 + t;
        int j = g % 576, kq = g / 576;
        unsigned s0 = f2bf(Wh[(kq * 4 + 0) * 576 + j]);
        unsigned s1 = f2bf(Wh[(kq * 4 + 1) * 576 + j]);
        unsigned s2 = f2bf(Wh[(kq * 4 + 2) * 576 + j]);
        unsigned s3 = f2bf(Wh[(kq * 4 + 3) * 576 + j]);
        *(uint2*)(Whb + kq * 2304 + j * 4) = make_uint2(s0 | (s1 << 16), s2 | (s3 << 16));
    } else if (blk < 624) {                // W1b4
        int g = (blk - 576) * 256 + t;
        int j = g % 256, kq = g / 256;
        unsigned s0 = f2bf(W1[(kq * 4 + 0) * 256 + j]);
        unsigned s1 = f2bf(W1[(kq * 4 + 1) * 256 + j]);
        unsigned s2 = f2bf(W1[(kq * 4 + 2) * 256 + j]);
        unsigned s3 = f2bf(W1[(kq * 4 + 3) * 256 + j]);
        *(uint2*)(W1b + kq * 1024 + j * 4) = make_uint2(s0 | (s1 << 16), s2 | (s3 << 16));
    } else {                               // W2b4
        int g = (blk - 624) * 256 + t;
        int j = g % 192, kq = g / 192;     // kq 0..63
        unsigned s0 = f2bf(W2[(kq * 4 + 0) * 192 + j]);
        unsigned s1 = f2bf(W2[(kq * 4 + 1) * 192 + j]);
        unsigned s2 = f2bf(W2[(kq * 4 + 2) * 192 + j]);
        unsigned s3 = f2bf(W2[(kq * 4 + 3) * 192 + j]);
        *(uint2*)(W2b + kq * 768 + j * 4) = make_uint2(s0 | (s1 << 16), s2 | (s3 << 16));
    }
}

// ---------------------------------------------------------------- phase A v7: r1 tile EXACT, + batched-ILP LN + B dbuf
// Only two changes vs the 110.8-us r1 kernel: (1) LN as 2 batches of 8 rows
// (loads in flight, level-major butterflies; bitwise-same per-row math),
// (2) B fragments double-buffered across kk (no arithmetic change).
__global__ __launch_bounds__(256) void k_lnkv(
    const float* __restrict__ x, const float* __restrict__ lng, const float* __restrict__ lnb,
    const unsigned short* __restrict__ Wt, unsigned short* __restrict__ xkv)
{
    __shared__ unsigned short lds[64 * 320];        // 40 KB
    const int t = threadIdx.x, wave = t >> 6, lane = t & 63;
    const int l15 = lane & 15, lg = lane >> 4;
    const long rowbase = (long)blockIdx.x * 64;

    float4 gv = *(const float4*)(lng + lane * 4);
    float4 bv = *(const float4*)(lnb + lane * 4);

    #pragma unroll
    for (int bat = 0; bat < 2; ++bat) {
        float4 xr[8];
        #pragma unroll
        for (int r = 0; r < 8; ++r)
            xr[r] = *(const float4*)(x + (rowbase + wave * 16 + bat * 8 + r) * 256 + lane * 4);
        float s1[8], s2[8];
        #pragma unroll
        for (int r = 0; r < 8; ++r) {
            s1[r] = xr[r].x + xr[r].y + xr[r].z + xr[r].w;
            s2[r] = xr[r].x * xr[r].x + xr[r].y * xr[r].y + xr[r].z * xr[r].z + xr[r].w * xr[r].w;
        }
        #pragma unroll
        for (int o = 32; o > 0; o >>= 1) {
            #pragma unroll
            for (int r = 0; r < 8; ++r) {
                s1[r] += __shfl_xor(s1[r], o);
                s2[r] += __shfl_xor(s2[r], o);
            }
        }
        #pragma unroll
        for (int r = 0; r < 8; ++r) {
            int row = wave * 16 + bat * 8 + r;
            float mean = s1[r] * (1.f / 256.f);
            float var  = s2[r] * (1.f / 256.f) - mean * mean;
            float rstd = rsqrtf(var + 1e-5f);
            float y0 = (xr[r].x - mean) * rstd * gv.x + bv.x;
            float y1 = (xr[r].y - mean) * rstd * gv.y + bv.y;
            float y2 = (xr[r].z - mean) * rstd * gv.z + bv.z;
            float y3 = (xr[r].w - mean) * rstd * gv.w + bv.w;
            unsigned int u0 = (unsigned)f2bf(y0) | ((unsigned)f2bf(y1) << 16);
            unsigned int u1 = (unsigned)f2bf(y2) | ((unsigned)f2bf(y3) << 16);
            int off = row * 512 + ((lane * 8) ^ ((row & 7) << 4));
            *(uint2*)((char*)lds + off) = make_uint2(u0, u1);
        }
    }
    __syncthreads();

    f32x4 acc[4][5];
    #pragma unroll
    for (int mt = 0; mt < 4; ++mt)
        #pragma unroll
        for (int nt = 0; nt < 5; ++nt) acc[mt][nt] = (f32x4){0.f, 0.f, 0.f, 0.f};

    const int nb = wave * 80;
    s16x8 bcur[5], bnxt[5];
    #pragma unroll
    for (int nt = 0; nt < 5; ++nt)
        bcur[nt] = *(const s16x8*)(Wt + (nb + nt * 16 + l15) * 256 + lg * 8);

    #pragma unroll
    for (int kk = 0; kk < 8; ++kk) {
        if (kk < 7) {
            #pragma unroll
            for (int nt = 0; nt < 5; ++nt)
                bnxt[nt] = *(const s16x8*)(Wt + (nb + nt * 16 + l15) * 256 + (kk + 1) * 32 + lg * 8);
        }
        s16x8 a[4];
        #pragma unroll
        for (int mt = 0; mt < 4; ++mt) {
            int row = mt * 16 + l15;
            int off = row * 512 + ((kk * 64 + lg * 16) ^ ((row & 7) << 4));
            a[mt] = *(const s16x8*)((char*)lds + off);
        }
        #pragma unroll
        for (int mt = 0; mt < 4; ++mt)
            #pragma unroll
            for (int nt = 0; nt < 5; ++nt)
                acc[mt][nt] = mfma16(a[mt], bcur[nt], acc[mt][nt]);
        #pragma unroll
        for (int nt = 0; nt < 5; ++nt) bcur[nt] = bnxt[nt];
    }
    __syncthreads();

    #pragma unroll
    for (int mt = 0; mt < 4; ++mt)
        #pragma unroll
        for (int nt = 0; nt < 5; ++nt)
            #pragma unroll
            for (int rg = 0; rg < 4; ++rg) {
                int row = mt * 16 + lg * 4 + rg;
                int col = nb + nt * 16 + l15;
                lds[row * 320 + col] = f2bf(acc[mt][nt][rg]);
            }
    __syncthreads();
    const uint4* src = (const uint4*)lds;
    uint4* dst = (uint4*)(xkv + rowbase * 320);
    #pragma unroll
    for (int j = 0; j < 10; ++j) dst[j * 256 + t] = src[j * 256 + t];
}

// ---------------------------------------------------------------- per-iter: q v3 (r18 verbatim)
__global__ __launch_bounds__(384) void k_qry(
    const float* __restrict__ sview, const float* __restrict__ sattr,
    const float* __restrict__ fnewp, int use_fnew,
    const float* __restrict__ lng, const float* __restrict__ lnb,
    const float* __restrict__ Wq, float* __restrict__ full, unsigned short* __restrict__ qbf)
{
    int row = blockIdx.x;                  // bv*7 + s
    int bv = row / 7, s = row % 7, b = bv >> 2;
    int j = threadIdx.x;
    __shared__ float fr[192];
    __shared__ float part[384];
    __shared__ float red[8];
    float v = 0.f;
    if (j < 192) {
        if (use_fnew) {
            if (j < 64) {
                float a = 0.f;
                #pragma unroll
                for (int sp = 0; sp < 7; ++sp) a += fnewp[(bv * 7 + sp) * 192 + j];
                v = a * (1.f / 7.f);
            } else {
                float a = 0.f;
                #pragma unroll
                for (int vv = 0; vv < 4; ++vv) a += fnewp[((b * 4 + vv) * 7 + s) * 192 + j];
                v = a * 0.25f;
            }
        } else {
            v = (j < 64) ? sview[bv * 64 + j] : sattr[(b * 7 + s) * 128 + (j - 64)];
        }
        full[row * 192 + j] = v;
        float s1 = v, s2 = v * v;
        #pragma unroll
        for (int o = 32; o > 0; o >>= 1) { s1 += __shfl_xor(s1, o); s2 += __shfl_xor(s2, o); }
        int wave = j >> 6, lane = j & 63;
        if (lane == 0) { red[wave] = s1; red[4 + wave] = s2; }
    }
    __syncthreads();
    if (j < 192) {
        float ts = red[0] + red[1] + red[2], ts2 = red[4] + red[5] + red[6];
        float mean = ts * (1.f / 192.f);
        float var  = ts2 * (1.f / 192.f) - mean * mean;
        float rstd = rsqrtf(var + 1e-5f);
        fr[j] = (v - mean) * rstd * lng[j] + lnb[j];
    }
    __syncthreads();
    {
        int c = j & 127, seg = j >> 7;               // 3 segments x 64 k
        float acc = 0.f;
        #pragma unroll
        for (int k = 0; k < 64; ++k) acc += fr[seg * 64 + k] * Wq[(seg * 64 + k) * 128 + c];
        part[j] = acc;
    }
    __syncthreads();
    if (j < 128) {
        float acc = part[j] + part[128 + j] + part[256 + j];
        qbf[(bv * 16 + s) * 128 + j] = f2bf(acc * COEF);
    }
}

// ---------------------------------------------------------------- per-iter: fused attn+upd v3 (r18 verbatim)
__global__ __launch_bounds__(256) void k_attu(
    const unsigned short* __restrict__ qbf, const unsigned short* __restrict__ xkv,
    float* __restrict__ pU, float* __restrict__ pZ)
{
    int blk = blockIdx.x;                  // 512 = 32 bv * 16 chunks(256 n)
    int bv = blk >> 4, chunk = blk & 15;
    int n0 = chunk * 256;
    int t = threadIdx.x, wave = t >> 6, lane = t & 63;
    int l15 = lane & 15, lg = lane >> 4;
    __shared__ float wl[256 * 8];

    s16x8 aq[4];
    const unsigned short* qrow = qbf + (bv * 16 + l15) * 128 + lg * 8;
    #pragma unroll
    for (int kk = 0; kk < 4; ++kk) aq[kk] = *(const s16x8*)(qrow + kk * 32);

    #pragma unroll
    for (int batch = 0; batch < 4; ++batch) {
        int nloc = batch * 64 + wave * 16;
        const unsigned short* xr = xkv + ((long)(bv * 4096 + n0 + nloc + l15)) * 320 + lg * 8;
        f32x4 acc = (f32x4){0.f, 0.f, 0.f, 0.f};
        #pragma unroll
        for (int kk = 0; kk < 4; ++kk) {
            s16x8 bfr = *(const s16x8*)(xr + kk * 32);
            acc = mfma16(aq[kk], bfr, acc);
        }
        float o0 = __shfl_xor(acc[0], 16), o1 = __shfl_xor(acc[1], 16);
        float o2 = __shfl_xor(acc[2], 16), o3 = __shfl_xor(acc[3], 16);
        bool hi = (lg & 1);
        float v0 = hi ? o0 : acc[0], v1 = hi ? o1 : acc[1];
        float v2 = hi ? o2 : acc[2], v3 = hi ? o3 : acc[3];
        float v4 = hi ? acc[0] : o0, v5 = hi ? acc[1] : o1, v6 = hi ? acc[2] : o2;
        float m = fmaxf(fmaxf(fmaxf(v0, v1), fmaxf(v2, v3)), fmaxf(fmaxf(v4, v5), v6));
        float e0 = __expf(v0 - m), e1 = __expf(v1 - m), e2 = __expf(v2 - m), e3 = __expf(v3 - m);
        float e4 = __expf(v4 - m), e5 = __expf(v5 - m), e6 = __expf(v6 - m);
        float inv = 1.f / (e0 + e1 + e2 + e3 + e4 + e5 + e6);
        if (lg < 2) {
            int n = nloc + l15;                // LOCAL row index 0..255
            float4 out = (lg == 0) ? make_float4(e0 * inv, e1 * inv, e2 * inv, e3 * inv)
                                   : make_float4(e4 * inv, e5 * inv, e6 * inv, 0.f);
            *(float4*)(wl + n * 8 + lg * 4) = out;
        }
    }
    __syncthreads();

    {
        f32x4 uacc[3];
        #pragma unroll
        for (int it = 0; it < 3; ++it) uacc[it] = (f32x4){0.f, 0.f, 0.f, 0.f};
        const unsigned short* vbase = xkv + ((long)(bv * 4096 + n0)) * 320 + 128;

        #pragma unroll
        for (int kb = 0; kb < 8; ++kb) {
            s16x8 aw = (s16x8){0, 0, 0, 0, 0, 0, 0, 0};
            if (l15 < 8) {
                #pragma unroll
                for (int j2 = 0; j2 < 8; ++j2)
                    aw[j2] = (short)f2bf(wl[(kb * 32 + lg * 8 + j2) * 8 + l15]);
            }
            #pragma unroll
            for (int it = 0; it < 3; ++it) {
                int col = wave * 48 + it * 16 + l15;
                s16x8 bw;
                #pragma unroll
                for (int j2 = 0; j2 < 8; ++j2)
                    bw[j2] = (short)vbase[(long)(kb * 32 + lg * 8 + j2) * 320 + col];
                uacc[it] = mfma16(aw, bw, uacc[it]);
            }
        }

        long base = (((long)bv * 16 + chunk) * 7) * 192;
        #pragma unroll
        for (int it = 0; it < 3; ++it) {
            int col = wave * 48 + it * 16 + l15;
            #pragma unroll
            for (int rg = 0; rg < 4; ++rg) {
                int s = lg * 4 + rg;
                if (s < 7) pU[base + s * 192 + col] = uacc[it][rg];
            }
        }
    }

    if (t < 112) {
        int s = t >> 4, part = t & 15;
        float z = 0.f;
        #pragma unroll
        for (int k = 0; k < 16; ++k) z += wl[(part + 16 * k) * 8 + s];
        #pragma unroll
        for (int o = 8; o > 0; o >>= 1) z += __shfl_xor(z, o);
        if (part == 0) pZ[(bv * 16 + chunk) * 7 + s] = z;
    }
}

// ---------------------------------------------------------------- per-iter: GRU+MLP v6 (r18 verbatim)
__global__ __launch_bounds__(576) void k_gru(
    const float* __restrict__ pU, const float* __restrict__ pZ, const float* __restrict__ full,
    const unsigned short* __restrict__ Wib, const unsigned short* __restrict__ Whb,
    const float* __restrict__ bi, const float* __restrict__ bh,
    const float* __restrict__ lng, const float* __restrict__ lnb,
    const unsigned short* __restrict__ W1b, const float* __restrict__ b1,
    const unsigned short* __restrict__ W2b, const float* __restrict__ b2,
    float* __restrict__ fnew)
{
    int row = blockIdx.x;                  // bv*7 + s
    int bv = row / 7, s = row % 7;
    int j = threadIdx.x;
    __shared__ float u[192], h[192], gi[576], gh[576], lnm[192], h1[256], red[8];

    if (j < 192) {
        float u0 = 0.f, u1 = 0.f, u2 = 0.f, u3 = 0.f;
        #pragma unroll
        for (int c = 0; c < 16; c += 4) {
            u0 += pU[(((long)bv * 16 + c + 0) * 7 + s) * 192 + j];
            u1 += pU[(((long)bv * 16 + c + 1) * 7 + s) * 192 + j];
            u2 += pU[(((long)bv * 16 + c + 2) * 7 + s) * 192 + j];
            u3 += pU[(((long)bv * 16 + c + 3) * 7 + s) * 192 + j];
        }
        float z0 = 0.f, z1 = 0.f, z2 = 0.f, z3 = 0.f;
        #pragma unroll
        for (int c = 0; c < 16; c += 4) {
            z0 += pZ[(bv * 16 + c + 0) * 7 + s];
            z1 += pZ[(bv * 16 + c + 1) * 7 + s];
            z2 += pZ[(bv * 16 + c + 2) * 7 + s];
            z3 += pZ[(bv * 16 + c + 3) * 7 + s];
        }
        u[j] = ((u0 + u1) + (u2 + u3)) / ((z0 + z1) + (z2 + z3));
    } else if (j < 384) {
        int jj = j - 192;
        h[jj] = full[row * 192 + jj];
    }
    __syncthreads();

    {
        float a0 = 0.f, a1 = 0.f, a2 = 0.f, a3 = 0.f;
        float b0 = 0.f, b1v = 0.f, b2v = 0.f, b3 = 0.f;
        #pragma unroll 4
        for (int kq = 0; kq < 48; ++kq) {
            uint2 wi = *(const uint2*)(Wib + kq * 2304 + j * 4);
            uint2 wh = *(const uint2*)(Whb + kq * 2304 + j * 4);
            int k = kq * 4;
            a0  += u[k + 0] * bf2f((unsigned short)(wi.x & 0xffffu));
            a1  += u[k + 1] * bf2f((unsigned short)(wi.x >> 16));
            a2  += u[k + 2] * bf2f((unsigned short)(wi.y & 0xffffu));
            a3  += u[k + 3] * bf2f((unsigned short)(wi.y >> 16));
            b0  += h[k + 0] * bf2f((unsigned short)(wh.x & 0xffffu));
            b1v += h[k + 1] * bf2f((unsigned short)(wh.x >> 16));
            b2v += h[k + 2] * bf2f((unsigned short)(wh.y & 0xffffu));
            b3  += h[k + 3] * bf2f((unsigned short)(wh.y >> 16));
        }
        gi[j] = ((a0 + a1) + (a2 + a3)) + bi[j];
        gh[j] = ((b0 + b1v) + (b2v + b3)) + bh[j];
    }
    __syncthreads();

    float mn = 0.f;
    if (j < 192) {
        float hv = h[j];
        float r  = 1.f / (1.f + __expf(-(gi[j] + gh[j])));
        float z  = 1.f / (1.f + __expf(-(gi[192 + j] + gh[192 + j])));
        float nn = tanhf(gi[384 + j] + r * gh[384 + j]);
        mn = (1.f - z) * nn + z * hv;

        float s1 = mn, s2 = mn * mn;
        #pragma unroll
        for (int o = 32; o > 0; o >>= 1) { s1 += __shfl_xor(s1, o); s2 += __shfl_xor(s2, o); }
        int wave = j >> 6, lane = j & 63;
        if (lane == 0) { red[wave] = s1; red[4 + wave] = s2; }
    }
    __syncthreads();
    if (j < 192) {
        float ts = red[0] + red[1] + red[2], ts2 = red[4] + red[5] + red[6];
        float mean = ts * (1.f / 192.f);
        float var  = ts2 * (1.f / 192.f) - mean * mean;
        float rstd = rsqrtf(var + 1e-5f);
        lnm[j] = (mn - mean) * rstd * lng[j] + lnb[j];
    }
    __syncthreads();

    if (j < 256) {
        float a0 = 0.f, a1 = 0.f, a2 = 0.f, a3 = 0.f;
        #pragma unroll 4
        for (int kq = 0; kq < 48; ++kq) {
            uint2 w1 = *(const uint2*)(W1b + kq * 1024 + j * 4);
            int k = kq * 4;
            a0 += lnm[k + 0] * bf2f((unsigned short)(w1.x & 0xffffu));
            a1 += lnm[k + 1] * bf2f((unsigned short)(w1.x >> 16));
            a2 += lnm[k + 2] * bf2f((unsigned short)(w1.y & 0xffffu));
            a3 += lnm[k + 3] * bf2f((unsigned short)(w1.y >> 16));
        }
        h1[j] = fmaxf(((a0 + a1) + (a2 + a3)) + b1[j], 0.f);
    }
    __syncthreads();

    if (j < 192) {
        float a0 = 0.f, a1 = 0.f, a2 = 0.f, a3 = 0.f;
        #pragma unroll 4
        for (int cq = 0; cq < 64; ++cq) {
            uint2 w2 = *(const uint2*)(W2b + cq * 768 + j * 4);
            int c = cq * 4;
            a0 += h1[c + 0] * bf2f((unsigned short)(w2.x & 0xffffu));
            a1 += h1[c + 1] * bf2f((unsigned short)(w2.x >> 16));
            a2 += h1[c + 2] * bf2f((unsigned short)(w2.y & 0xffffu));
            a3 += h1[c + 3] * bf2f((unsigned short)(w2.y >> 16));
        }
        fnew[row * 192 + j] = mn + (((a0 + a1) + (a2 + a3)) + b2[j]);
    }
}

// ---------------------------------------------------------------- final: slot means -> d_out (r18 verbatim)
__global__ __launch_bounds__(256) void k_means(
    const float* __restrict__ fnew, float* __restrict__ oview, float* __restrict__ oattr)
{
    int t = blockIdx.x * 256 + threadIdx.x;
    if (t < 2048) {
        int bv = t >> 6, d = t & 63;
        float a = 0.f;
        #pragma unroll
        for (int s = 0; s < 7; ++s) a += fnew[(bv * 7 + s) * 192 + d];
        oview[t] = a * (1.f / 7.f);
    } else if (t < 9216) {
        int u = t - 2048;
        int b = u / 896, r = u % 896, s = r >> 7, d = r & 127;
        float a = 0.f;
        #pragma unroll
        for (int v = 0; v < 4; ++v) a += fnew[((b * 4 + v) * 7 + s) * 192 + 64 + d];
        oattr[u] = a * 0.25f;
    }
}

// ---------------------------------------------------------------- host
extern "C" void kernel_launch(void* const* d_in, const int* in_sizes, int n_in,
                              void* d_out, int out_size, void* d_ws, size_t ws_size,
                              hipStream_t stream)
{
    const float* x          = (const float*)d_in[0];
    const float* noise_view = (const float*)d_in[1];
    const float* noise_obj  = (const float*)d_in[2];
    const float* noise_bck  = (const float*)d_in[3];
    const float* ln_in_g    = (const float*)d_in[4];
    const float* ln_in_b    = (const float*)d_in[5];
    const float* ln_qry_g   = (const float*)d_in[6];
    const float* ln_qry_b   = (const float*)d_in[7];
    const float* ln_res_g   = (const float*)d_in[8];
    const float* ln_res_b   = (const float*)d_in[9];
    const float* view_loc   = (const float*)d_in[10];
    const float* view_lscl  = (const float*)d_in[11];
    const float* ao_loc     = (const float*)d_in[12];
    const float* ao_scl     = (const float*)d_in[13];
    const float* ab_loc     = (const float*)d_in[14];
    const float* ab_scl     = (const float*)d_in[15];
    const float* W_qry      = (const float*)d_in[16];
    const float* W_key      = (const float*)d_in[17];
    const float* W_val      = (const float*)d_in[18];
    const float* gru_Wi     = (const float*)d_in[19];
    const float* gru_Wh     = (const float*)d_in[20];
    const float* gru_bi     = (const float*)d_in[21];
    const float* gru_bh     = (const float*)d_in[22];
    const float* mlp_W1     = (const float*)d_in[23];
    const float* mlp_b1     = (const float*)d_in[24];
    const float* mlp_W2     = (const float*)d_in[25];
    const float* mlp_b2     = (const float*)d_in[26];

    char* ws = (char*)d_ws;
    size_t off = 0;
    auto alloc = [&](size_t bytes) { void* p = ws + off; off += (bytes + 255) & ~255ULL; return p; };
    unsigned short* xkv = (unsigned short*)alloc(131072UL * 320 * 2);   // 80 MB
    unsigned short* Wt  = (unsigned short*)alloc(320UL * 256 * 2);
    unsigned short* qbf = (unsigned short*)alloc(32UL * 16 * 128 * 2);
    float* pU    = (float*)alloc(32UL * 16 * 7 * 192 * 4);              // 2.75 MB
    float* pZ    = (float*)alloc(32UL * 16 * 7 * 4);
    float* fullb = (float*)alloc(224UL * 192 * 4);
    float* fnew  = (float*)alloc(224UL * 192 * 4);
    float* sview = (float*)alloc(2048UL * 4);
    float* sattr = (float*)alloc(7168UL * 4);
    unsigned short* Wib = (unsigned short*)alloc(110592UL * 2);
    unsigned short* Whb = (unsigned short*)alloc(110592UL * 2);
    unsigned short* W1b = (unsigned short*)alloc(49152UL * 2);
    unsigned short* W2b = (unsigned short*)alloc(49152UL * 2);

    k_prep<<<dim3(672), dim3(256), 0, stream>>>(
        W_key, W_val, view_loc, view_lscl, noise_view,
        ao_loc, ao_scl, noise_obj, ab_loc, ab_scl, noise_bck,
        gru_Wi, gru_Wh, mlp_W1, mlp_W2,
        Wt, qbf, sview, sattr, Wib, Whb, W1b, W2b);
    k_lnkv<<<dim3(2048), dim3(256), 0, stream>>>(x, ln_in_g, ln_in_b, Wt, xkv);

    for (int it = 0; it < 3; ++it) {
        k_qry<<<dim3(224), dim3(384), 0, stream>>>(sview, sattr, fnew, (it > 0) ? 1 : 0,
                                                   ln_qry_g, ln_qry_b, W_qry, fullb, qbf);
        k_attu<<<dim3(512), dim3(256), 0, stream>>>(qbf, xkv, pU, pZ);
        k_gru<<<dim3(224), dim3(576), 0, stream>>>(pU, pZ, fullb, Wib, Whb, gru_bi, gru_bh,
                                                   ln_res_g, ln_res_b, W1b, mlp_b1, W2b, mlp_b2, fnew);
    }
    k_means<<<dim3(36), dim3(256), 0, stream>>>(fnew, (float*)d_out, ((float*)d_out) + 2048);
}